// Round 1
// baseline (4103.602 us; speedup 1.0000x reference)
//
#include <hip/hip_runtime.h>
#include <math.h>

#define B_ 32
#define N_ 4096

// ---------------------------------------------------------------------------
// FPS: one block per batch. Replicates jax.lax.scan FPS exactly:
// idx[0]=0; iteratively update mind with plain-fp32 (no FMA) distances,
// argmax with first-index tie-break.
// ---------------------------------------------------------------------------
template<int N, int NPOINT, int NT>
__global__ void fps_kernel(const float* __restrict__ xyz,
                           int* __restrict__ outIdx,
                           float* __restrict__ outXyz) {
#pragma clang fp contract(off)
    const int b = blockIdx.x;
    const int t = threadIdx.x;
    constexpr int PPT = N / NT;
    constexpr int NW = (NT + 63) / 64;
    __shared__ float xs[N], ys[N], zs[N];
    __shared__ float redV[NW];
    __shared__ int   redI[NW];
    __shared__ int   curIdx;
    __shared__ int   fidxS[NPOINT];
    const float* base = xyz + (size_t)b * N * 3;
    for (int j = t; j < N; j += NT) {
        xs[j] = base[j * 3 + 0];
        ys[j] = base[j * 3 + 1];
        zs[j] = base[j * 3 + 2];
    }
    __syncthreads();
    float px[PPT], py[PPT], pz[PPT], mind[PPT];
#pragma unroll
    for (int i = 0; i < PPT; i++) {
        int p = t + i * NT;
        px[i] = xs[p]; py[i] = ys[p]; pz[i] = zs[p];
        mind[i] = 1e10f;
    }
    if (t == 0) fidxS[0] = 0;
    int last = 0;
    for (int it = 1; it < NPOINT; it++) {
        float lx = xs[last], ly = ys[last], lz = zs[last];
        float bv = -1.0f; int bi = 0;
#pragma unroll
        for (int i = 0; i < PPT; i++) {
            float dx = px[i] - lx, dy = py[i] - ly, dz = pz[i] - lz;
            float t0 = dx * dx, t1 = dy * dy, t2 = dz * dz;
            float d = (t0 + t1) + t2;
            float m = fminf(mind[i], d);
            mind[i] = m;
            int p = t + i * NT;
            if (m > bv) { bv = m; bi = p; }   // ascending p => first-max kept
        }
        // wave64 butterfly reduce (max value, min index on tie)
#pragma unroll
        for (int off = 32; off > 0; off >>= 1) {
            float ov = __shfl_xor(bv, off);
            int   oi = __shfl_xor(bi, off);
            if (ov > bv || (ov == bv && oi < bi)) { bv = ov; bi = oi; }
        }
        if constexpr (NT > 64) {
            if ((t & 63) == 0) { redV[t >> 6] = bv; redI[t >> 6] = bi; }
            __syncthreads();
            if (t == 0) {
#pragma unroll
                for (int w = 1; w < NW; w++) {
                    float ov = redV[w]; int oi = redI[w];
                    if (ov > bv || (ov == bv && oi < bi)) { bv = ov; bi = oi; }
                }
                curIdx = bi; fidxS[it] = bi;
            }
            __syncthreads();
            last = curIdx;
        } else {
            last = bi;
            if (t == 0) fidxS[it] = bi;
        }
    }
    __syncthreads();
    for (int s = t; s < NPOINT; s += NT) {
        int id = fidxS[s];
        outIdx[b * NPOINT + s] = id;
        outXyz[(b * NPOINT + s) * 3 + 0] = xs[id];
        outXyz[(b * NPOINT + s) * 3 + 1] = ys[id];
        outXyz[(b * NPOINT + s) * 3 + 2] = zs[id];
    }
}

// ---------------------------------------------------------------------------
// Ball query: gid = first NS indices (ascending) with sqd <= r2, pad with
// first.  sqd = (|q|^2 + |p|^2) - 2*dot, plain fp32, matching reference.
// One thread per query.
// ---------------------------------------------------------------------------
template<int N, int NS, int NT, int CHUNKS>
__global__ void ballquery_kernel(const float* __restrict__ xyz,
                                 const float* __restrict__ newXyz,
                                 int* __restrict__ outIdx,
                                 int S, float r2) {
#pragma clang fp contract(off)
    const int b = blockIdx.x / CHUNKS;
    const int chunk = blockIdx.x % CHUNKS;
    const int t = threadIdx.x;
    __shared__ float xs[N], ys[N], zs[N];
    const float* base = xyz + (size_t)b * N * 3;
    for (int j = t; j < N; j += NT) {
        xs[j] = base[j * 3 + 0];
        ys[j] = base[j * 3 + 1];
        zs[j] = base[j * 3 + 2];
    }
    __syncthreads();
    const int s = chunk * NT + t;
    const float* q = newXyz + ((size_t)b * S + s) * 3;
    float qx = q[0], qy = q[1], qz = q[2];
    float qn = (qx * qx + qy * qy) + qz * qz;
    int* dst = outIdx + ((size_t)b * S + s) * NS;
    int cnt = 0, first = 0;
    for (int p = 0; p < N; p++) {
        float x = xs[p], y = ys[p], z = zs[p];
        float pn = (x * x + y * y) + z * z;
        float dot = (qx * x + qy * y) + qz * z;
        float sqd = (qn + pn) - 2.0f * dot;
        if (sqd <= r2) {
            if (cnt == 0) first = p;
            dst[cnt++] = p;
            if (cnt == NS) break;
        }
    }
    for (int i = cnt; i < NS; i++) dst[i] = first;
}

// ---------------------------------------------------------------------------
// SA1 fused MLP: one 64-thread block per group (b,s). 3->64->64->128, relu,
// max over 32 neighbors. Weights rows held in registers, activations in LDS
// (reads are wave-broadcast).
// ---------------------------------------------------------------------------
__global__ __launch_bounds__(64) void sa1_mlp_kernel(
    const float* __restrict__ x, const float* __restrict__ newXyz,
    const int* __restrict__ idx,
    const float* __restrict__ w0, const float* __restrict__ b0,
    const float* __restrict__ w1, const float* __restrict__ b1,
    const float* __restrict__ w2, const float* __restrict__ b2,
    float* __restrict__ feat) {
    const int g = blockIdx.x;           // b*512+s
    const int b = g >> 9;
    const int t = threadIdx.x;          // 0..63
    __shared__ float gx[32][3];
    __shared__ float h1[32][64];
    __shared__ float h2[32][64];
    if (t < 32) {
        int id = idx[(size_t)g * 32 + t];
        const float* pp = x + ((size_t)b * N_ + id) * 3;
        const float* cc = newXyz + (size_t)g * 3;
        gx[t][0] = pp[0] - cc[0];
        gx[t][1] = pp[1] - cc[1];
        gx[t][2] = pp[2] - cc[2];
    }
    __syncthreads();
    {   // layer1: 3 -> 64
        float wa = w0[t * 3 + 0], wb = w0[t * 3 + 1], wc = w0[t * 3 + 2];
        float bb = b0[t];
#pragma unroll 4
        for (int k = 0; k < 32; k++) {
            float v = bb + wa * gx[k][0] + wb * gx[k][1] + wc * gx[k][2];
            h1[k][t] = fmaxf(v, 0.f);
        }
    }
    __syncthreads();
    {   // layer2: 64 -> 64
        float wr[64];
#pragma unroll
        for (int c = 0; c < 64; c++) wr[c] = w1[t * 64 + c];
        float bb = b1[t];
        for (int k = 0; k < 32; k += 2) {
            float a0 = bb, a1 = bb;
#pragma unroll
            for (int c = 0; c < 64; c++) {
                a0 += wr[c] * h1[k][c];
                a1 += wr[c] * h1[k + 1][c];
            }
            h2[k][t] = fmaxf(a0, 0.f);
            h2[k + 1][t] = fmaxf(a1, 0.f);
        }
    }
    __syncthreads();
    float m0 = 0.f, m1 = 0.f;   // relu outputs are >= 0
    {   // layer3: 64 -> 128 (two channels per thread) + max over k
        float wa[64], wb[64];
#pragma unroll
        for (int c = 0; c < 64; c++) {
            wa[c] = w2[t * 64 + c];
            wb[c] = w2[(t + 64) * 64 + c];
        }
        float ba = b2[t], bb2 = b2[t + 64];
        for (int k = 0; k < 32; k++) {
            float a0 = ba, a1 = bb2;
#pragma unroll
            for (int c = 0; c < 64; c++) {
                a0 += wa[c] * h2[k][c];
                a1 += wb[c] * h2[k][c];
            }
            m0 = fmaxf(m0, fmaxf(a0, 0.f));
            m1 = fmaxf(m1, fmaxf(a1, 0.f));
        }
    }
    feat[(size_t)g * 128 + t] = m0;
    feat[(size_t)g * 128 + t + 64] = m1;
}

// ---------------------------------------------------------------------------
// SA2 fused MLP: one 128-thread block per group (b,s). Channels:
// 131 -> 128 -> 128 -> 256, relu, max over 64 neighbors. Processed in two
// 32-neighbor halves to keep LDS under 64 KB (49.8 KB -> 3 blocks/CU).
// ---------------------------------------------------------------------------
__global__ __launch_bounds__(128) void sa2_mlp_kernel(
    const float* __restrict__ xyz1,   // (B,512,3)
    const float* __restrict__ feat1,  // (B,512,128)
    const float* __restrict__ newXyz, // (B,128,3)
    const int* __restrict__ idx,      // (B,128,64)
    const float* __restrict__ w0, const float* __restrict__ b0, // 128x131
    const float* __restrict__ w1, const float* __restrict__ b1, // 128x128
    const float* __restrict__ w2, const float* __restrict__ b2, // 256x128
    float* __restrict__ feat2) {      // (B,128,256)
    const int g = blockIdx.x;          // b*128+s
    const int b = g >> 7;
    const int t = threadIdx.x;         // 0..127
    __shared__ int   ids[64];
    __shared__ float gbuf[32 * 131];
    __shared__ float h1[32 * 128];
    __shared__ float h2[32 * 128];
    if (t < 64) ids[t] = idx[(size_t)g * 64 + t];
    const float* cc = newXyz + (size_t)g * 3;
    float cx = cc[0], cy = cc[1], cz = cc[2];
    float m0 = 0.f, m1 = 0.f;
    for (int half = 0; half < 2; half++) {
        __syncthreads();
        // gather 32 rows: [dx,dy,dz, feat1[0..127]]
        for (int k = 0; k < 32; k++) {
            int id = ids[half * 32 + k];
            gbuf[k * 131 + 3 + t] = feat1[((size_t)b * 512 + id) * 128 + t];
        }
        if (t < 32) {
            int id = ids[half * 32 + t];
            const float* pp = xyz1 + ((size_t)b * 512 + id) * 3;
            gbuf[t * 131 + 0] = pp[0] - cx;
            gbuf[t * 131 + 1] = pp[1] - cy;
            gbuf[t * 131 + 2] = pp[2] - cz;
        }
        __syncthreads();
        {   // layer1: 131 -> 128
            float wr[131];
#pragma unroll
            for (int c = 0; c < 131; c++) wr[c] = w0[t * 131 + c];
            float bb = b0[t];
            for (int k = 0; k < 32; k += 2) {
                float a0 = bb, a1 = bb;
#pragma unroll
                for (int c = 0; c < 131; c++) {
                    a0 += wr[c] * gbuf[k * 131 + c];
                    a1 += wr[c] * gbuf[(k + 1) * 131 + c];
                }
                h1[k * 128 + t] = fmaxf(a0, 0.f);
                h1[(k + 1) * 128 + t] = fmaxf(a1, 0.f);
            }
        }
        __syncthreads();
        {   // layer2: 128 -> 128
            float wr[128];
#pragma unroll
            for (int c = 0; c < 128; c++) wr[c] = w1[t * 128 + c];
            float bb = b1[t];
            for (int k = 0; k < 32; k += 2) {
                float a0 = bb, a1 = bb;
#pragma unroll
                for (int c = 0; c < 128; c++) {
                    a0 += wr[c] * h1[k * 128 + c];
                    a1 += wr[c] * h1[(k + 1) * 128 + c];
                }
                h2[k * 128 + t] = fmaxf(a0, 0.f);
                h2[(k + 1) * 128 + t] = fmaxf(a1, 0.f);
            }
        }
        __syncthreads();
        {   // layer3: 128 -> 256 (two passes of 128 channels) + running max
            float wr[128];
#pragma unroll
            for (int c = 0; c < 128; c++) wr[c] = w2[t * 128 + c];
            float bb = b2[t];
            for (int k = 0; k < 32; k += 2) {
                float a0 = bb, a1 = bb;
#pragma unroll
                for (int c = 0; c < 128; c++) {
                    a0 += wr[c] * h2[k * 128 + c];
                    a1 += wr[c] * h2[(k + 1) * 128 + c];
                }
                m0 = fmaxf(m0, fmaxf(a0, 0.f));
                m0 = fmaxf(m0, fmaxf(a1, 0.f));
            }
#pragma unroll
            for (int c = 0; c < 128; c++) wr[c] = w2[(t + 128) * 128 + c];
            bb = b2[t + 128];
            for (int k = 0; k < 32; k += 2) {
                float a0 = bb, a1 = bb;
#pragma unroll
                for (int c = 0; c < 128; c++) {
                    a0 += wr[c] * h2[k * 128 + c];
                    a1 += wr[c] * h2[(k + 1) * 128 + c];
                }
                m1 = fmaxf(m1, fmaxf(a0, 0.f));
                m1 = fmaxf(m1, fmaxf(a1, 0.f));
            }
        }
    }
    feat2[(size_t)g * 256 + t] = m0;
    feat2[(size_t)g * 256 + t + 128] = m1;
}

// ---------------------------------------------------------------------------
// concat [xyz2(3) | feat2(256)] -> A3 (4096 x 259)
// ---------------------------------------------------------------------------
__global__ void concat3_kernel(const float* __restrict__ xyz2,
                               const float* __restrict__ feat2,
                               float* __restrict__ a3, int total) {
    int i = blockIdx.x * 256 + threadIdx.x;
    if (i >= total) return;
    int m = i / 259, c = i % 259;
    a3[i] = (c < 3) ? xyz2[m * 3 + c] : feat2[m * 256 + (c - 3)];
}

// ---------------------------------------------------------------------------
// GEMM: out[m][o] = act(bias[o] + sum_k A[m][k]*W[o][k]).  128x128 tile,
// BK=8, 256 threads, 8x8 accum per thread. M,O multiples of 128; K ragged.
// ---------------------------------------------------------------------------
template<int RELU>
__global__ __launch_bounds__(256) void gemm_bias_kernel(
    const float* __restrict__ A, const float* __restrict__ W,
    const float* __restrict__ bias, float* __restrict__ out,
    int M, int K, int O) {
    const int bo = blockIdx.x, bm = blockIdx.y;
    const int t = threadIdx.x;
    __shared__ float As[8][132];
    __shared__ float Ws[8][132];
    const int tx = t & 15;      // o-subtile
    const int ty = t >> 4;      // m-subtile
    const int lr = t >> 1;      // staging row 0..127
    const int lh = (t & 1) * 4; // staging k offset
    const int m0 = bm * 128, o0 = bo * 128;
    float acc[8][8] = {};
    for (int kt = 0; kt < K; kt += 8) {
#pragma unroll
        for (int j = 0; j < 4; j++) {
            int k = kt + lh + j;
            As[lh + j][lr] = (k < K) ? A[(size_t)(m0 + lr) * K + k] : 0.f;
            Ws[lh + j][lr] = (k < K) ? W[(size_t)(o0 + lr) * K + k] : 0.f;
        }
        __syncthreads();
#pragma unroll
        for (int kk = 0; kk < 8; kk++) {
            float a[8], w[8];
#pragma unroll
            for (int i = 0; i < 8; i++) a[i] = As[kk][ty * 8 + i];
#pragma unroll
            for (int i = 0; i < 8; i++) w[i] = Ws[kk][tx * 8 + i];
#pragma unroll
            for (int i = 0; i < 8; i++)
#pragma unroll
                for (int j2 = 0; j2 < 8; j2++)
                    acc[i][j2] += a[i] * w[j2];
        }
        __syncthreads();
    }
#pragma unroll
    for (int i = 0; i < 8; i++) {
        int m = m0 + ty * 8 + i;
#pragma unroll
        for (int j2 = 0; j2 < 8; j2++) {
            int o = o0 + tx * 8 + j2;
            float v = acc[i][j2] + bias[o];
            if (RELU) v = fmaxf(v, 0.f);
            out[(size_t)m * O + o] = v;
        }
    }
}

// ---------------------------------------------------------------------------
// max over 128 points: (32,128,1024) -> (32,1024)
// ---------------------------------------------------------------------------
__global__ void maxpool_kernel(const float* __restrict__ in,
                               float* __restrict__ out) {
    int b = blockIdx.x, t = threadIdx.x;
#pragma unroll
    for (int j = 0; j < 4; j++) {
        int o = t + j * 256;
        float m = -INFINITY;
        for (int k = 0; k < 128; k++)
            m = fmaxf(m, in[((size_t)b * 128 + k) * 1024 + o]);
        out[b * 1024 + o] = m;
    }
}

// ---------------------------------------------------------------------------
// FC head: 1024->512 relu ->256 relu ->40, softmax.  One block per batch row.
// ---------------------------------------------------------------------------
__global__ __launch_bounds__(256) void fc_head_kernel(
    const float* __restrict__ gfeat,
    const float* __restrict__ w1, const float* __restrict__ b1,
    const float* __restrict__ w2, const float* __restrict__ b2,
    const float* __restrict__ w3, const float* __restrict__ b3,
    float* __restrict__ out) {
    int b = blockIdx.x, t = threadIdx.x;
    __shared__ float f[1024];
    __shared__ float h1[512];
    __shared__ float h2[256];
    __shared__ float lg[40];
    for (int j = t; j < 1024; j += 256) f[j] = gfeat[b * 1024 + j];
    __syncthreads();
#pragma unroll
    for (int rep = 0; rep < 2; rep++) {
        int o = t + rep * 256;
        float a = b1[o];
        for (int c = 0; c < 1024; c++) a += w1[(size_t)o * 1024 + c] * f[c];
        h1[o] = fmaxf(a, 0.f);
    }
    __syncthreads();
    {
        float a = b2[t];
        for (int c = 0; c < 512; c++) a += w2[t * 512 + c] * h1[c];
        h2[t] = fmaxf(a, 0.f);
    }
    __syncthreads();
    if (t < 40) {
        float a = b3[t];
        for (int c = 0; c < 256; c++) a += w3[t * 256 + c] * h2[c];
        lg[t] = a;
    }
    __syncthreads();
    if (t < 64) {
        float v = (t < 40) ? lg[t] : -INFINITY;
        float m = v;
#pragma unroll
        for (int off = 32; off > 0; off >>= 1) m = fmaxf(m, __shfl_xor(m, off));
        float e = (t < 40) ? expf(v - m) : 0.f;
        float s = e;
#pragma unroll
        for (int off = 32; off > 0; off >>= 1) s += __shfl_xor(s, off);
        if (t < 40) out[b * 40 + t] = e / s;
    }
}

// ---------------------------------------------------------------------------
extern "C" void kernel_launch(void* const* d_in, const int* in_sizes, int n_in,
                              void* d_out, int out_size, void* d_ws, size_t ws_size,
                              hipStream_t stream) {
    (void)in_sizes; (void)n_in; (void)out_size; (void)ws_size;
    const float* x      = (const float*)d_in[0];
    const float* sa1w0  = (const float*)d_in[1];
    const float* sa1b0  = (const float*)d_in[2];
    const float* sa1w1  = (const float*)d_in[3];
    const float* sa1b1  = (const float*)d_in[4];
    const float* sa1w2  = (const float*)d_in[5];
    const float* sa1b2  = (const float*)d_in[6];
    const float* sa2w0  = (const float*)d_in[7];
    const float* sa2b0  = (const float*)d_in[8];
    const float* sa2w1  = (const float*)d_in[9];
    const float* sa2b1  = (const float*)d_in[10];
    const float* sa2w2  = (const float*)d_in[11];
    const float* sa2b2  = (const float*)d_in[12];
    const float* sa3w0  = (const float*)d_in[13];
    const float* sa3b0  = (const float*)d_in[14];
    const float* sa3w1  = (const float*)d_in[15];
    const float* sa3b1  = (const float*)d_in[16];
    const float* sa3w2  = (const float*)d_in[17];
    const float* sa3b2  = (const float*)d_in[18];
    const float* fc1w   = (const float*)d_in[19];
    const float* fc1b   = (const float*)d_in[20];
    const float* fc2w   = (const float*)d_in[21];
    const float* fc2b   = (const float*)d_in[22];
    const float* fc3w   = (const float*)d_in[23];
    const float* fc3b   = (const float*)d_in[24];
    float* outp = (float*)d_out;

    // workspace layout
    char* ws = (char*)d_ws;
    size_t off = 0;
    auto alloc = [&](size_t bytes) {
        void* p = ws + off;
        off += (bytes + 255) & ~(size_t)255;
        return p;
    };
    int*   fidx1   = (int*)  alloc((size_t)B_ * 512 * 4);
    float* nxyz1   = (float*)alloc((size_t)B_ * 512 * 3 * 4);
    int*   idx1    = (int*)  alloc((size_t)B_ * 512 * 32 * 4);
    float* feat1   = (float*)alloc((size_t)B_ * 512 * 128 * 4);
    int*   fidx2   = (int*)  alloc((size_t)B_ * 128 * 4);
    float* nxyz2   = (float*)alloc((size_t)B_ * 128 * 3 * 4);
    int*   idx2    = (int*)  alloc((size_t)B_ * 128 * 64 * 4);
    float* feat2   = (float*)alloc((size_t)B_ * 128 * 256 * 4);
    float* a3      = (float*)alloc((size_t)4096 * 259 * 4);
    float* h3a     = (float*)alloc((size_t)4096 * 256 * 4);
    float* h3b     = (float*)alloc((size_t)4096 * 512 * 4);
    float* h3c     = (float*)alloc((size_t)4096 * 1024 * 4);
    float* gfeat   = (float*)alloc((size_t)B_ * 1024 * 4);

    // SA1
    fps_kernel<4096, 512, 512><<<B_, 512, 0, stream>>>(x, fidx1, nxyz1);
    ballquery_kernel<4096, 32, 256, 2><<<B_ * 2, 256, 0, stream>>>(
        x, nxyz1, idx1, 512, 0.04f);
    sa1_mlp_kernel<<<B_ * 512, 64, 0, stream>>>(
        x, nxyz1, idx1, sa1w0, sa1b0, sa1w1, sa1b1, sa1w2, sa1b2, feat1);
    // SA2
    fps_kernel<512, 128, 64><<<B_, 64, 0, stream>>>(nxyz1, fidx2, nxyz2);
    ballquery_kernel<512, 64, 128, 1><<<B_, 128, 0, stream>>>(
        nxyz1, nxyz2, idx2, 128, 0.16f);
    sa2_mlp_kernel<<<B_ * 128, 128, 0, stream>>>(
        nxyz1, feat1, nxyz2, idx2, sa2w0, sa2b0, sa2w1, sa2b1, sa2w2, sa2b2,
        feat2);
    // SA3 (group-all): concat + 3 GEMMs + maxpool
    concat3_kernel<<<(4096 * 259 + 255) / 256, 256, 0, stream>>>(
        nxyz2, feat2, a3, 4096 * 259);
    gemm_bias_kernel<1><<<dim3(2, 32), 256, 0, stream>>>(
        a3, sa3w0, sa3b0, h3a, 4096, 259, 256);
    gemm_bias_kernel<1><<<dim3(4, 32), 256, 0, stream>>>(
        h3a, sa3w1, sa3b1, h3b, 4096, 256, 512);
    gemm_bias_kernel<1><<<dim3(8, 32), 256, 0, stream>>>(
        h3b, sa3w2, sa3b2, h3c, 4096, 512, 1024);
    maxpool_kernel<<<B_, 256, 0, stream>>>(h3c, gfeat);
    // FC head + softmax
    fc_head_kernel<<<B_, 256, 0, stream>>>(
        gfeat, fc1w, fc1b, fc2w, fc2b, fc3w, fc3b, outp);
}

// Round 2
// 3773.468 us; speedup vs baseline: 1.0875x; 1.0875x over previous
//
#include <hip/hip_runtime.h>
#include <math.h>

#define B_ 32
#define N_ 4096

// ---------------------------------------------------------------------------
// FPS: one block per batch. Replicates jax.lax.scan FPS exactly:
// idx[0]=0; iteratively update mind with plain-fp32 (no FMA) distances,
// argmax with first-index tie-break.
// ---------------------------------------------------------------------------
template<int N, int NPOINT, int NT>
__global__ void fps_kernel(const float* __restrict__ xyz,
                           int* __restrict__ outIdx,
                           float* __restrict__ outXyz) {
#pragma clang fp contract(off)
    const int b = blockIdx.x;
    const int t = threadIdx.x;
    constexpr int PPT = N / NT;
    constexpr int NW = (NT + 63) / 64;
    __shared__ float xs[N], ys[N], zs[N];
    __shared__ float redV[NW];
    __shared__ int   redI[NW];
    __shared__ int   curIdx;
    __shared__ int   fidxS[NPOINT];
    const float* base = xyz + (size_t)b * N * 3;
    for (int j = t; j < N; j += NT) {
        xs[j] = base[j * 3 + 0];
        ys[j] = base[j * 3 + 1];
        zs[j] = base[j * 3 + 2];
    }
    __syncthreads();
    float px[PPT], py[PPT], pz[PPT], mind[PPT];
#pragma unroll
    for (int i = 0; i < PPT; i++) {
        int p = t + i * NT;
        px[i] = xs[p]; py[i] = ys[p]; pz[i] = zs[p];
        mind[i] = 1e10f;
    }
    if (t == 0) fidxS[0] = 0;
    int last = 0;
    for (int it = 1; it < NPOINT; it++) {
        float lx = xs[last], ly = ys[last], lz = zs[last];
        float bv = -1.0f; int bi = 0;
#pragma unroll
        for (int i = 0; i < PPT; i++) {
            float dx = px[i] - lx, dy = py[i] - ly, dz = pz[i] - lz;
            float t0 = dx * dx, t1 = dy * dy, t2 = dz * dz;
            float d = (t0 + t1) + t2;
            float m = fminf(mind[i], d);
            mind[i] = m;
            int p = t + i * NT;
            if (m > bv) { bv = m; bi = p; }   // ascending p => first-max kept
        }
        // wave64 butterfly reduce (max value, min index on tie)
#pragma unroll
        for (int off = 32; off > 0; off >>= 1) {
            float ov = __shfl_xor(bv, off);
            int   oi = __shfl_xor(bi, off);
            if (ov > bv || (ov == bv && oi < bi)) { bv = ov; bi = oi; }
        }
        if constexpr (NT > 64) {
            if ((t & 63) == 0) { redV[t >> 6] = bv; redI[t >> 6] = bi; }
            __syncthreads();
            if (t == 0) {
#pragma unroll
                for (int w = 1; w < NW; w++) {
                    float ov = redV[w]; int oi = redI[w];
                    if (ov > bv || (ov == bv && oi < bi)) { bv = ov; bi = oi; }
                }
                curIdx = bi; fidxS[it] = bi;
            }
            __syncthreads();
            last = curIdx;
        } else {
            last = bi;
            if (t == 0) fidxS[it] = bi;
        }
    }
    __syncthreads();
    for (int s = t; s < NPOINT; s += NT) {
        int id = fidxS[s];
        outIdx[b * NPOINT + s] = id;
        outXyz[(b * NPOINT + s) * 3 + 0] = xs[id];
        outXyz[(b * NPOINT + s) * 3 + 1] = ys[id];
        outXyz[(b * NPOINT + s) * 3 + 2] = zs[id];
    }
}

// ---------------------------------------------------------------------------
// Ball query (unchanged, correct).
// ---------------------------------------------------------------------------
template<int N, int NS, int NT, int CHUNKS>
__global__ void ballquery_kernel(const float* __restrict__ xyz,
                                 const float* __restrict__ newXyz,
                                 int* __restrict__ outIdx,
                                 int S, float r2) {
#pragma clang fp contract(off)
    const int b = blockIdx.x / CHUNKS;
    const int chunk = blockIdx.x % CHUNKS;
    const int t = threadIdx.x;
    __shared__ float xs[N], ys[N], zs[N];
    const float* base = xyz + (size_t)b * N * 3;
    for (int j = t; j < N; j += NT) {
        xs[j] = base[j * 3 + 0];
        ys[j] = base[j * 3 + 1];
        zs[j] = base[j * 3 + 2];
    }
    __syncthreads();
    const int s = chunk * NT + t;
    const float* q = newXyz + ((size_t)b * S + s) * 3;
    float qx = q[0], qy = q[1], qz = q[2];
    float qn = (qx * qx + qy * qy) + qz * qz;
    int* dst = outIdx + ((size_t)b * S + s) * NS;
    int cnt = 0, first = 0;
    for (int p = 0; p < N; p++) {
        float x = xs[p], y = ys[p], z = zs[p];
        float pn = (x * x + y * y) + z * z;
        float dot = (qx * x + qy * y) + qz * z;
        float sqd = (qn + pn) - 2.0f * dot;
        if (sqd <= r2) {
            if (cnt == 0) first = p;
            dst[cnt++] = p;
            if (cnt == NS) break;
        }
    }
    for (int i = cnt; i < NS; i++) dst[i] = first;
}

// ---------------------------------------------------------------------------
// Shared-MLP layer core: lane = neighbor, activations transposed in LDS
// (tin[c*64+lane]), weights via wave-uniform scalar loads (SGPR operands).
// Each wave computes OW output channels starting at o0 for all 64 lanes.
// ---------------------------------------------------------------------------
template<int CIN, int OW>
__device__ __forceinline__ void mlp_layer(const float* tin, float* tout,
                                          const float* __restrict__ w,
                                          const float* __restrict__ bias,
                                          int o0, int lane) {
    float acc[OW];
#pragma unroll
    for (int i = 0; i < OW; i++) acc[i] = bias[o0 + i];
    constexpr int NCH = CIN / 8;
#pragma unroll 2
    for (int cc = 0; cc < NCH; cc++) {
        const int c0 = cc * 8;
        float a[8];
#pragma unroll
        for (int j = 0; j < 8; j++) a[j] = tin[(c0 + j) * 64 + lane];
#pragma unroll
        for (int i = 0; i < OW; i++) {
            const float* wr = w + (size_t)(o0 + i) * CIN + c0;
#pragma unroll
            for (int j = 0; j < 8; j++) acc[i] = fmaf(wr[j], a[j], acc[i]);
        }
    }
    if constexpr ((CIN % 8) != 0) {
        constexpr int REM = CIN % 8;
        const int c0 = NCH * 8;
        float a[REM];
#pragma unroll
        for (int j = 0; j < REM; j++) a[j] = tin[(c0 + j) * 64 + lane];
#pragma unroll
        for (int i = 0; i < OW; i++) {
            const float* wr = w + (size_t)(o0 + i) * CIN + c0;
#pragma unroll
            for (int j = 0; j < REM; j++) acc[i] = fmaf(wr[j], a[j], acc[i]);
        }
    }
#pragma unroll
    for (int i = 0; i < OW; i++) tout[(o0 + i) * 64 + lane] = fmaxf(acc[i], 0.f);
}

// Final layer + relu + max over all 64 lanes (RED=64) or 32-lane halves
// (RED=32, two groups per wave). out: RED=64 -> out[o]; RED=32 ->
// out[(lane>>5)*outHalfStride + o].
template<int CIN, int OW, int RED>
__device__ __forceinline__ void mlp_layer_max(const float* tin,
                                              const float* __restrict__ w,
                                              const float* __restrict__ bias,
                                              int o0, int lane,
                                              float* out, int outHalfStride) {
    float acc[OW];
#pragma unroll
    for (int i = 0; i < OW; i++) acc[i] = bias[o0 + i];
    constexpr int NCH = CIN / 8;
#pragma unroll 2
    for (int cc = 0; cc < NCH; cc++) {
        const int c0 = cc * 8;
        float a[8];
#pragma unroll
        for (int j = 0; j < 8; j++) a[j] = tin[(c0 + j) * 64 + lane];
#pragma unroll
        for (int i = 0; i < OW; i++) {
            const float* wr = w + (size_t)(o0 + i) * CIN + c0;
#pragma unroll
            for (int j = 0; j < 8; j++) acc[i] = fmaf(wr[j], a[j], acc[i]);
        }
    }
#pragma unroll
    for (int i = 0; i < OW; i++) {
        float v = fmaxf(acc[i], 0.f);   // relu outputs >=0, so max init implicit
        if constexpr (RED == 64) {
#pragma unroll
            for (int off = 32; off > 0; off >>= 1) v = fmaxf(v, __shfl_xor(v, off));
            if (lane == 0) out[o0 + i] = v;
        } else {
#pragma unroll
            for (int off = 16; off > 0; off >>= 1) v = fmaxf(v, __shfl_xor(v, off));
            if ((lane & 31) == 0)
                out[(lane >> 5) * outHalfStride + o0 + i] = v;
        }
    }
}

// ---------------------------------------------------------------------------
// SA1 fused MLP v2: 256 threads = 4 waves, 2 groups per block (one per
// 32-lane half). 3->64->64->128, relu, max over 32 neighbors.
// Weights: scalar loads. Activations transposed in LDS. No spills.
// ---------------------------------------------------------------------------
__global__ __launch_bounds__(256) void sa1_mlp_kernel(
    const float* __restrict__ x, const float* __restrict__ newXyz,
    const int* __restrict__ idx,
    const float* __restrict__ w0, const float* __restrict__ b0,
    const float* __restrict__ w1, const float* __restrict__ b1,
    const float* __restrict__ w2, const float* __restrict__ b2,
    float* __restrict__ feat) {
    const int g0 = blockIdx.x * 2;       // first of 2 groups
    const int b = g0 >> 9;
    const int t = threadIdx.x;
    const int lane = t & 63;
    const int wv = t >> 6;
    __shared__ float gx[3][64];
    __shared__ float h1[64][64];
    __shared__ float h2[64][64];
    if (t < 64) {
        int g = g0 + (t >> 5);
        int id = idx[(size_t)g * 32 + (t & 31)];
        const float* pp = x + ((size_t)b * N_ + id) * 3;
        const float* cc = newXyz + (size_t)g * 3;
        gx[0][t] = pp[0] - cc[0];
        gx[1][t] = pp[1] - cc[1];
        gx[2][t] = pp[2] - cc[2];
    }
    __syncthreads();
    {   // layer1: 3 -> 64 (16 channels per wave)
        int o0 = __builtin_amdgcn_readfirstlane(wv * 16);
        float a0 = gx[0][lane], a1 = gx[1][lane], a2 = gx[2][lane];
#pragma unroll
        for (int i = 0; i < 16; i++) {
            int o = o0 + i;
            float v = fmaf(w0[o * 3 + 0], a0,
                      fmaf(w0[o * 3 + 1], a1,
                      fmaf(w0[o * 3 + 2], a2, b0[o])));
            h1[o][lane] = fmaxf(v, 0.f);
        }
    }
    __syncthreads();
    {   // layer2: 64 -> 64
        int o0 = __builtin_amdgcn_readfirstlane(wv * 16);
        mlp_layer<64, 16>(&h1[0][0], &h2[0][0], w1, b1, o0, lane);
    }
    __syncthreads();
    {   // layer3: 64 -> 128 + max over 32 neighbors (per half-wave group)
        int o0 = __builtin_amdgcn_readfirstlane(wv * 32);
        mlp_layer_max<64, 32, 32>(&h2[0][0], w2, b2, o0, lane,
                                  feat + (size_t)g0 * 128, 128);
    }
}

// ---------------------------------------------------------------------------
// SA2 fused MLP v2: 256 threads = 4 waves, one group per block, lane =
// neighbor (64). 131->128->128->256, relu, max over 64 neighbors.
// LDS: tin[131][64] (g, then reused as h2) + t1[128][64] (h1) = 66.5 KB.
// ---------------------------------------------------------------------------
__global__ __launch_bounds__(256) void sa2_mlp_kernel(
    const float* __restrict__ xyz1,   // (B,512,3)
    const float* __restrict__ feat1,  // (B,512,128)
    const float* __restrict__ newXyz, // (B,128,3)
    const int* __restrict__ idx,      // (B,128,64)
    const float* __restrict__ w0, const float* __restrict__ b0, // 128x131
    const float* __restrict__ w1, const float* __restrict__ b1, // 128x128
    const float* __restrict__ w2, const float* __restrict__ b2, // 256x128
    float* __restrict__ feat2) {      // (B,128,256)
    const int g = blockIdx.x;          // b*128+s
    const int b = g >> 7;
    const int t = threadIdx.x;
    const int lane = t & 63;
    const int wv = t >> 6;
    __shared__ int   ids[64];
    __shared__ float tin[131][64];     // g input, later h2 (rows 0..127)
    __shared__ float t1[128][64];      // h1
    if (t < 64) ids[t] = idx[(size_t)g * 64 + t];
    __syncthreads();
    {   // gather transposed: tin[c][k]
        int id = ids[lane];
        const float* fp = feat1 + ((size_t)b * 512 + id) * 128;
        for (int c = wv; c < 128; c += 4) tin[3 + c][lane] = fp[c];
        if (t < 64) {
            const float* pp = xyz1 + ((size_t)b * 512 + id) * 3;
            const float* cc = newXyz + (size_t)g * 3;
            tin[0][t] = pp[0] - cc[0];
            tin[1][t] = pp[1] - cc[1];
            tin[2][t] = pp[2] - cc[2];
        }
    }
    __syncthreads();
    {   // layer1: 131 -> 128 (32 ch/wave), g(tin) -> h1(t1)
        int o0 = __builtin_amdgcn_readfirstlane(wv * 32);
        mlp_layer<131, 32>(&tin[0][0], &t1[0][0], w0, b0, o0, lane);
    }
    __syncthreads();
    {   // layer2: 128 -> 128, h1(t1) -> h2(tin)
        int o0 = __builtin_amdgcn_readfirstlane(wv * 32);
        mlp_layer<128, 32>(&t1[0][0], &tin[0][0], w1, b1, o0, lane);
    }
    __syncthreads();
    {   // layer3: 128 -> 256 (64 ch/wave) + max over 64 neighbors
        int o0 = __builtin_amdgcn_readfirstlane(wv * 64);
        mlp_layer_max<128, 64, 64>(&tin[0][0], w2, b2, o0, lane,
                                   feat2 + (size_t)g * 256, 0);
    }
}

// ---------------------------------------------------------------------------
// concat [xyz2(3) | feat2(256)] -> A3 (4096 x 259)
// ---------------------------------------------------------------------------
__global__ void concat3_kernel(const float* __restrict__ xyz2,
                               const float* __restrict__ feat2,
                               float* __restrict__ a3, int total) {
    int i = blockIdx.x * 256 + threadIdx.x;
    if (i >= total) return;
    int m = i / 259, c = i % 259;
    a3[i] = (c < 3) ? xyz2[m * 3 + c] : feat2[m * 256 + (c - 3)];
}

// ---------------------------------------------------------------------------
// GEMM: out[m][o] = act(bias[o] + sum_k A[m][k]*W[o][k]).  128x128 tile,
// BK=8, 256 threads, 8x8 accum per thread.
// ---------------------------------------------------------------------------
template<int RELU>
__global__ __launch_bounds__(256) void gemm_bias_kernel(
    const float* __restrict__ A, const float* __restrict__ W,
    const float* __restrict__ bias, float* __restrict__ out,
    int M, int K, int O) {
    const int bo = blockIdx.x, bm = blockIdx.y;
    const int t = threadIdx.x;
    __shared__ float As[8][132];
    __shared__ float Ws[8][132];
    const int tx = t & 15;
    const int ty = t >> 4;
    const int lr = t >> 1;
    const int lh = (t & 1) * 4;
    const int m0 = bm * 128, o0 = bo * 128;
    float acc[8][8] = {};
    for (int kt = 0; kt < K; kt += 8) {
#pragma unroll
        for (int j = 0; j < 4; j++) {
            int k = kt + lh + j;
            As[lh + j][lr] = (k < K) ? A[(size_t)(m0 + lr) * K + k] : 0.f;
            Ws[lh + j][lr] = (k < K) ? W[(size_t)(o0 + lr) * K + k] : 0.f;
        }
        __syncthreads();
#pragma unroll
        for (int kk = 0; kk < 8; kk++) {
            float a[8], w[8];
#pragma unroll
            for (int i = 0; i < 8; i++) a[i] = As[kk][ty * 8 + i];
#pragma unroll
            for (int i = 0; i < 8; i++) w[i] = Ws[kk][tx * 8 + i];
#pragma unroll
            for (int i = 0; i < 8; i++)
#pragma unroll
                for (int j2 = 0; j2 < 8; j2++)
                    acc[i][j2] += a[i] * w[j2];
        }
        __syncthreads();
    }
#pragma unroll
    for (int i = 0; i < 8; i++) {
        int m = m0 + ty * 8 + i;
#pragma unroll
        for (int j2 = 0; j2 < 8; j2++) {
            int o = o0 + tx * 8 + j2;
            float v = acc[i][j2] + bias[o];
            if (RELU) v = fmaxf(v, 0.f);
            out[(size_t)m * O + o] = v;
        }
    }
}

// ---------------------------------------------------------------------------
// max over 128 points: (32,128,1024) -> (32,1024)
// ---------------------------------------------------------------------------
__global__ void maxpool_kernel(const float* __restrict__ in,
                               float* __restrict__ out) {
    int b = blockIdx.x, t = threadIdx.x;
#pragma unroll
    for (int j = 0; j < 4; j++) {
        int o = t + j * 256;
        float m = -INFINITY;
        for (int k = 0; k < 128; k++)
            m = fmaxf(m, in[((size_t)b * 128 + k) * 1024 + o]);
        out[b * 1024 + o] = m;
    }
}

// ---------------------------------------------------------------------------
// FC head: 1024->512 relu ->256 relu ->40, softmax.  One block per batch row.
// ---------------------------------------------------------------------------
__global__ __launch_bounds__(256) void fc_head_kernel(
    const float* __restrict__ gfeat,
    const float* __restrict__ w1, const float* __restrict__ b1,
    const float* __restrict__ w2, const float* __restrict__ b2,
    const float* __restrict__ w3, const float* __restrict__ b3,
    float* __restrict__ out) {
    int b = blockIdx.x, t = threadIdx.x;
    __shared__ float f[1024];
    __shared__ float h1[512];
    __shared__ float h2[256];
    __shared__ float lg[40];
    for (int j = t; j < 1024; j += 256) f[j] = gfeat[b * 1024 + j];
    __syncthreads();
#pragma unroll
    for (int rep = 0; rep < 2; rep++) {
        int o = t + rep * 256;
        float a = b1[o];
        for (int c = 0; c < 1024; c++) a += w1[(size_t)o * 1024 + c] * f[c];
        h1[o] = fmaxf(a, 0.f);
    }
    __syncthreads();
    {
        float a = b2[t];
        for (int c = 0; c < 512; c++) a += w2[t * 512 + c] * h1[c];
        h2[t] = fmaxf(a, 0.f);
    }
    __syncthreads();
    if (t < 40) {
        float a = b3[t];
        for (int c = 0; c < 256; c++) a += w3[t * 256 + c] * h2[c];
        lg[t] = a;
    }
    __syncthreads();
    if (t < 64) {
        float v = (t < 40) ? lg[t] : -INFINITY;
        float m = v;
#pragma unroll
        for (int off = 32; off > 0; off >>= 1) m = fmaxf(m, __shfl_xor(m, off));
        float e = (t < 40) ? expf(v - m) : 0.f;
        float s = e;
#pragma unroll
        for (int off = 32; off > 0; off >>= 1) s += __shfl_xor(s, off);
        if (t < 40) out[b * 40 + t] = e / s;
    }
}

// ---------------------------------------------------------------------------
extern "C" void kernel_launch(void* const* d_in, const int* in_sizes, int n_in,
                              void* d_out, int out_size, void* d_ws, size_t ws_size,
                              hipStream_t stream) {
    (void)in_sizes; (void)n_in; (void)out_size; (void)ws_size;
    const float* x      = (const float*)d_in[0];
    const float* sa1w0  = (const float*)d_in[1];
    const float* sa1b0  = (const float*)d_in[2];
    const float* sa1w1  = (const float*)d_in[3];
    const float* sa1b1  = (const float*)d_in[4];
    const float* sa1w2  = (const float*)d_in[5];
    const float* sa1b2  = (const float*)d_in[6];
    const float* sa2w0  = (const float*)d_in[7];
    const float* sa2b0  = (const float*)d_in[8];
    const float* sa2w1  = (const float*)d_in[9];
    const float* sa2b1  = (const float*)d_in[10];
    const float* sa2w2  = (const float*)d_in[11];
    const float* sa2b2  = (const float*)d_in[12];
    const float* sa3w0  = (const float*)d_in[13];
    const float* sa3b0  = (const float*)d_in[14];
    const float* sa3w1  = (const float*)d_in[15];
    const float* sa3b1  = (const float*)d_in[16];
    const float* sa3w2  = (const float*)d_in[17];
    const float* sa3b2  = (const float*)d_in[18];
    const float* fc1w   = (const float*)d_in[19];
    const float* fc1b   = (const float*)d_in[20];
    const float* fc2w   = (const float*)d_in[21];
    const float* fc2b   = (const float*)d_in[22];
    const float* fc3w   = (const float*)d_in[23];
    const float* fc3b   = (const float*)d_in[24];
    float* outp = (float*)d_out;

    char* ws = (char*)d_ws;
    size_t off = 0;
    auto alloc = [&](size_t bytes) {
        void* p = ws + off;
        off += (bytes + 255) & ~(size_t)255;
        return p;
    };
    int*   fidx1   = (int*)  alloc((size_t)B_ * 512 * 4);
    float* nxyz1   = (float*)alloc((size_t)B_ * 512 * 3 * 4);
    int*   idx1    = (int*)  alloc((size_t)B_ * 512 * 32 * 4);
    float* feat1   = (float*)alloc((size_t)B_ * 512 * 128 * 4);
    int*   fidx2   = (int*)  alloc((size_t)B_ * 128 * 4);
    float* nxyz2   = (float*)alloc((size_t)B_ * 128 * 3 * 4);
    int*   idx2    = (int*)  alloc((size_t)B_ * 128 * 64 * 4);
    float* feat2   = (float*)alloc((size_t)B_ * 128 * 256 * 4);
    float* a3      = (float*)alloc((size_t)4096 * 259 * 4);
    float* h3a     = (float*)alloc((size_t)4096 * 256 * 4);
    float* h3b     = (float*)alloc((size_t)4096 * 512 * 4);
    float* h3c     = (float*)alloc((size_t)4096 * 1024 * 4);
    float* gfeat   = (float*)alloc((size_t)B_ * 1024 * 4);

    // SA1
    fps_kernel<4096, 512, 512><<<B_, 512, 0, stream>>>(x, fidx1, nxyz1);
    ballquery_kernel<4096, 32, 256, 2><<<B_ * 2, 256, 0, stream>>>(
        x, nxyz1, idx1, 512, 0.04f);
    sa1_mlp_kernel<<<B_ * 512 / 2, 256, 0, stream>>>(
        x, nxyz1, idx1, sa1w0, sa1b0, sa1w1, sa1b1, sa1w2, sa1b2, feat1);
    // SA2
    fps_kernel<512, 128, 64><<<B_, 64, 0, stream>>>(nxyz1, fidx2, nxyz2);
    ballquery_kernel<512, 64, 128, 1><<<B_, 128, 0, stream>>>(
        nxyz1, nxyz2, idx2, 128, 0.16f);
    sa2_mlp_kernel<<<B_ * 128, 256, 0, stream>>>(
        nxyz1, feat1, nxyz2, idx2, sa2w0, sa2b0, sa2w1, sa2b1, sa2w2, sa2b2,
        feat2);
    // SA3 (group-all): concat + 3 GEMMs + maxpool
    concat3_kernel<<<(4096 * 259 + 255) / 256, 256, 0, stream>>>(
        nxyz2, feat2, a3, 4096 * 259);
    gemm_bias_kernel<1><<<dim3(2, 32), 256, 0, stream>>>(
        a3, sa3w0, sa3b0, h3a, 4096, 259, 256);
    gemm_bias_kernel<1><<<dim3(4, 32), 256, 0, stream>>>(
        h3a, sa3w1, sa3b1, h3b, 4096, 256, 512);
    gemm_bias_kernel<1><<<dim3(8, 32), 256, 0, stream>>>(
        h3b, sa3w2, sa3b2, h3c, 4096, 512, 1024);
    maxpool_kernel<<<B_, 256, 0, stream>>>(h3c, gfeat);
    // FC head + softmax
    fc_head_kernel<<<B_, 256, 0, stream>>>(
        gfeat, fc1w, fc1b, fc2w, fc2b, fc3w, fc3b, outp);
}

// Round 3
// 2918.400 us; speedup vs baseline: 1.4061x; 1.2930x over previous
//
#include <hip/hip_runtime.h>
#include <math.h>

#define B_ 32
#define N_ 4096

typedef __attribute__((ext_vector_type(8))) short short8;
typedef __attribute__((ext_vector_type(4))) float f32x4;

// fp32 -> bf16 round-to-nearest-even, and split x = hi + lo (both bf16).
__device__ __forceinline__ unsigned short f2bf(float f) {
    unsigned u = __float_as_uint(f);
    unsigned r = 0x7FFFu + ((u >> 16) & 1u);
    return (unsigned short)((u + r) >> 16);
}
__device__ __forceinline__ float bf2f(unsigned short h) {
    return __uint_as_float(((unsigned)h) << 16);
}
__device__ __forceinline__ void f2bfpair(float v, short& h, short& l) {
    unsigned short hh = f2bf(v);
    h = (short)hh;
    l = (short)f2bf(v - bf2f(hh));
}

// ---------------------------------------------------------------------------
// FPS (exact fp32, index-critical — unchanged)
// ---------------------------------------------------------------------------
template<int N, int NPOINT, int NT>
__global__ void fps_kernel(const float* __restrict__ xyz,
                           int* __restrict__ outIdx,
                           float* __restrict__ outXyz) {
#pragma clang fp contract(off)
    const int b = blockIdx.x;
    const int t = threadIdx.x;
    constexpr int PPT = N / NT;
    constexpr int NW = (NT + 63) / 64;
    __shared__ float xs[N], ys[N], zs[N];
    __shared__ float redV[NW];
    __shared__ int   redI[NW];
    __shared__ int   curIdx;
    __shared__ int   fidxS[NPOINT];
    const float* base = xyz + (size_t)b * N * 3;
    for (int j = t; j < N; j += NT) {
        xs[j] = base[j * 3 + 0];
        ys[j] = base[j * 3 + 1];
        zs[j] = base[j * 3 + 2];
    }
    __syncthreads();
    float px[PPT], py[PPT], pz[PPT], mind[PPT];
#pragma unroll
    for (int i = 0; i < PPT; i++) {
        int p = t + i * NT;
        px[i] = xs[p]; py[i] = ys[p]; pz[i] = zs[p];
        mind[i] = 1e10f;
    }
    if (t == 0) fidxS[0] = 0;
    int last = 0;
    for (int it = 1; it < NPOINT; it++) {
        float lx = xs[last], ly = ys[last], lz = zs[last];
        float bv = -1.0f; int bi = 0;
#pragma unroll
        for (int i = 0; i < PPT; i++) {
            float dx = px[i] - lx, dy = py[i] - ly, dz = pz[i] - lz;
            float t0 = dx * dx, t1 = dy * dy, t2 = dz * dz;
            float d = (t0 + t1) + t2;
            float m = fminf(mind[i], d);
            mind[i] = m;
            int p = t + i * NT;
            if (m > bv) { bv = m; bi = p; }
        }
#pragma unroll
        for (int off = 32; off > 0; off >>= 1) {
            float ov = __shfl_xor(bv, off);
            int   oi = __shfl_xor(bi, off);
            if (ov > bv || (ov == bv && oi < bi)) { bv = ov; bi = oi; }
        }
        if constexpr (NT > 64) {
            if ((t & 63) == 0) { redV[t >> 6] = bv; redI[t >> 6] = bi; }
            __syncthreads();
            if (t == 0) {
#pragma unroll
                for (int w = 1; w < NW; w++) {
                    float ov = redV[w]; int oi = redI[w];
                    if (ov > bv || (ov == bv && oi < bi)) { bv = ov; bi = oi; }
                }
                curIdx = bi; fidxS[it] = bi;
            }
            __syncthreads();
            last = curIdx;
        } else {
            last = bi;
            if (t == 0) fidxS[it] = bi;
        }
    }
    __syncthreads();
    for (int s = t; s < NPOINT; s += NT) {
        int id = fidxS[s];
        outIdx[b * NPOINT + s] = id;
        outXyz[(b * NPOINT + s) * 3 + 0] = xs[id];
        outXyz[(b * NPOINT + s) * 3 + 1] = ys[id];
        outXyz[(b * NPOINT + s) * 3 + 2] = zs[id];
    }
}

// ---------------------------------------------------------------------------
// Ball query (exact fp32, index-critical — unchanged)
// ---------------------------------------------------------------------------
template<int N, int NS, int NT, int CHUNKS>
__global__ void ballquery_kernel(const float* __restrict__ xyz,
                                 const float* __restrict__ newXyz,
                                 int* __restrict__ outIdx,
                                 int S, float r2) {
#pragma clang fp contract(off)
    const int b = blockIdx.x / CHUNKS;
    const int chunk = blockIdx.x % CHUNKS;
    const int t = threadIdx.x;
    __shared__ float xs[N], ys[N], zs[N];
    const float* base = xyz + (size_t)b * N * 3;
    for (int j = t; j < N; j += NT) {
        xs[j] = base[j * 3 + 0];
        ys[j] = base[j * 3 + 1];
        zs[j] = base[j * 3 + 2];
    }
    __syncthreads();
    const int s = chunk * NT + t;
    const float* q = newXyz + ((size_t)b * S + s) * 3;
    float qx = q[0], qy = q[1], qz = q[2];
    float qn = (qx * qx + qy * qy) + qz * qz;
    int* dst = outIdx + ((size_t)b * S + s) * NS;
    int cnt = 0, first = 0;
    for (int p = 0; p < N; p++) {
        float x = xs[p], y = ys[p], z = zs[p];
        float pn = (x * x + y * y) + z * z;
        float dot = (qx * x + qy * y) + qz * z;
        float sqd = (qn + pn) - 2.0f * dot;
        if (sqd <= r2) {
            if (cnt == 0) first = p;
            dst[cnt++] = p;
            if (cnt == NS) break;
        }
    }
    for (int i = cnt; i < NS; i++) dst[i] = first;
}

// ---------------------------------------------------------------------------
// Weight prep: split fp32 [R][C] into bf16 hi/lo planes [R][Cp] (zero-padded)
// ---------------------------------------------------------------------------
__global__ void wprep_kernel(const float* __restrict__ src,
                             short* __restrict__ dh, short* __restrict__ dl,
                             int R, int C, int Cp) {
    int i = blockIdx.x * 256 + threadIdx.x;
    if (i >= R * Cp) return;
    int r = i / Cp, c = i % Cp;
    float v = (c < C) ? src[r * C + c] : 0.f;
    short h, l;
    f2bfpair(v, h, l);
    dh[i] = h; dl[i] = l;
}

// ---------------------------------------------------------------------------
// MFMA helpers. Verified gfx950 16x16x32 bf16 layouts:
//   A frag: lane holds A[m=lane&15][k=(lane>>4)*8 + j], j=0..7  (8 bf16, 16B)
//   B frag: lane holds B[n=lane&15][k=(lane>>4)*8 + j]          (W is [n][k])
//   C/D:    col(n)=lane&15, row(m)=(lane>>4)*4 + reg
// Split fp32 = hi+lo bf16: D += Ah*Bh + Ah*Bl + Al*Bh  (lo*lo dropped, 2^-18)
// Wave assignment: mh = m-half (2 m-tiles of 16), NT n-tiles per wave.
// ---------------------------------------------------------------------------
template<int NT, int KS>
__device__ __forceinline__ void mfma_layer(
    const short* Aph, const short* Apl, const int sA,
    const short* __restrict__ Wph, const short* __restrict__ Wpl, const int sW,
    f32x4* acc, const int n0, const int mh, const int lr, const int lq) {
#pragma unroll
    for (int ks = 0; ks < KS; ks++) {
        const int ka = ks * 32 + lq * 8;
        short8 a_h[2], a_l[2];
#pragma unroll
        for (int mt = 0; mt < 2; mt++) {
            const int m = (mh * 2 + mt) * 16 + lr;
            a_h[mt] = *(const short8*)(Aph + m * sA + ka);
            a_l[mt] = *(const short8*)(Apl + m * sA + ka);
        }
#pragma unroll
        for (int nt = 0; nt < NT; nt++) {
            const int n = n0 + nt * 16 + lr;
            short8 b_h = *(const short8*)(Wph + (size_t)n * sW + ka);
            short8 b_l = *(const short8*)(Wpl + (size_t)n * sW + ka);
#pragma unroll
            for (int mt = 0; mt < 2; mt++) {
                f32x4 c = acc[mt * NT + nt];
                c = __builtin_amdgcn_mfma_f32_16x16x32_bf16(a_h[mt], b_h, c, 0, 0, 0);
                c = __builtin_amdgcn_mfma_f32_16x16x32_bf16(a_h[mt], b_l, c, 0, 0, 0);
                c = __builtin_amdgcn_mfma_f32_16x16x32_bf16(a_l[mt], b_h, c, 0, 0, 0);
                acc[mt * NT + nt] = c;
            }
        }
    }
}

template<int NT>
__device__ __forceinline__ void init_bias(f32x4* acc, const float* __restrict__ bias,
                                          const int n0, const int lr) {
#pragma unroll
    for (int nt = 0; nt < NT; nt++) {
        float bv = bias[n0 + nt * 16 + lr];
        f32x4 c = {bv, bv, bv, bv};
        acc[0 * NT + nt] = c;
        acc[1 * NT + nt] = c;
    }
}

// relu + split into bf16 hi/lo planes at [m][n] (n = next layer's k)
template<int NT>
__device__ __forceinline__ void store_split(
    const f32x4* acc, short* Hp, short* Lp, const int stride,
    const int n0, const int mh, const int lr, const int lq) {
#pragma unroll
    for (int mt = 0; mt < 2; mt++)
#pragma unroll
        for (int nt = 0; nt < NT; nt++)
#pragma unroll
            for (int r = 0; r < 4; r++) {
                float v = fmaxf(acc[mt * NT + nt][r], 0.f);
                short h, l;
                f2bfpair(v, h, l);
                const int m = (mh * 2 + mt) * 16 + lq * 4 + r;
                const int n = n0 + nt * 16 + lr;
                Hp[m * stride + n] = h;
                Lp[m * stride + n] = l;
            }
}

// ---------------------------------------------------------------------------
// SA1 MFMA: block = 256 thr (4 waves) = 2 groups (64 rows = 2x32 neighbors).
// 3->64 (VALU) ->64 (MFMA) ->128 (MFMA) + per-group max.
// LDS ~38 KB -> 4 blocks/CU.
// ---------------------------------------------------------------------------
#define T1 72   // row stride (bf16) for K=64 planes; odd multiple of 8
__global__ __launch_bounds__(256) void sa1_mfma_kernel(
    const float* __restrict__ x, const float* __restrict__ nxyz1,
    const int* __restrict__ idx,
    const float* __restrict__ w0, const float* __restrict__ b0,
    const short* __restrict__ w1h, const short* __restrict__ w1l,
    const float* __restrict__ b1,
    const short* __restrict__ w2h, const short* __restrict__ w2l,
    const float* __restrict__ b2,
    float* __restrict__ feat1) {
    const int g0 = blockIdx.x * 2;
    const int b = g0 >> 9;
    const int t = threadIdx.x;
    const int lane = t & 63, wv = t >> 6;
    const int lr = lane & 15, lq = lane >> 4;
    const int mh = wv & 1, nh = wv >> 1;
    __shared__ float gx[64][4];
    __shared__ short H1h[64 * T1], H1l[64 * T1];
    __shared__ short H2h[64 * T1], H2l[64 * T1];
    if (t < 64) {
        int g = g0 + (t >> 5);
        int id = idx[(size_t)g * 32 + (t & 31)];
        const float* pp = x + ((size_t)b * N_ + id) * 3;
        const float* cc = nxyz1 + (size_t)g * 3;
        gx[t][0] = pp[0] - cc[0];
        gx[t][1] = pp[1] - cc[1];
        gx[t][2] = pp[2] - cc[2];
    }
    __syncthreads();
    {   // layer1 K=3 via VALU: thread -> (m = t>>2, 16 outputs at oc=(t&3)*16)
        const int m = t >> 2, oc = (t & 3) * 16;
        float a0 = gx[m][0], a1 = gx[m][1], a2 = gx[m][2];
        short8 hv0, hv1, lv0, lv1;
#pragma unroll
        for (int i = 0; i < 16; i++) {
            int o = oc + i;
            float v = fmaf(w0[o * 3 + 0], a0,
                      fmaf(w0[o * 3 + 1], a1,
                      fmaf(w0[o * 3 + 2], a2, b0[o])));
            v = fmaxf(v, 0.f);
            short h, l;
            f2bfpair(v, h, l);
            if (i < 8) { hv0[i] = h; lv0[i] = l; }
            else       { hv1[i - 8] = h; lv1[i - 8] = l; }
        }
        *(short8*)&H1h[m * T1 + oc]     = hv0;
        *(short8*)&H1h[m * T1 + oc + 8] = hv1;
        *(short8*)&H1l[m * T1 + oc]     = lv0;
        *(short8*)&H1l[m * T1 + oc + 8] = lv1;
    }
    __syncthreads();
    {   // layer2: K=64, N=64 -> NT=2 per wave (n0 = nh*32)
        f32x4 acc[4];
        init_bias<2>(acc, b1, nh * 32, lr);
        mfma_layer<2, 2>(H1h, H1l, T1, w1h, w1l, 64, acc, nh * 32, mh, lr, lq);
        store_split<2>(acc, H2h, H2l, T1, nh * 32, mh, lr, lq);
    }
    __syncthreads();
    {   // layer3: K=64, N=128 -> NT=4 per wave (n0 = nh*64) + per-group max
        f32x4 acc[8];
        init_bias<4>(acc, b2, nh * 64, lr);
        mfma_layer<4, 2>(H2h, H2l, T1, w2h, w2l, 64, acc, nh * 64, mh, lr, lq);
        // group = g0 + mh (rows mh*32..mh*32+31 are exactly this wave's tiles)
#pragma unroll
        for (int nt = 0; nt < 4; nt++) {
            float v = 0.f;   // relu floor
#pragma unroll
            for (int mt = 0; mt < 2; mt++)
#pragma unroll
                for (int r = 0; r < 4; r++)
                    v = fmaxf(v, acc[mt * 4 + nt][r]);
            v = fmaxf(v, __shfl_xor(v, 16));
            v = fmaxf(v, __shfl_xor(v, 32));
            if (lane < 16)
                feat1[(size_t)(g0 + mh) * 128 + nh * 64 + nt * 16 + lane] = v;
        }
    }
}

// ---------------------------------------------------------------------------
// SA2 MFMA: block = 256 thr (4 waves), one group (64 neighbors = 64 rows).
// 131->128->128->256 with K padded 131->160. LDS ~80 KB -> 2 blocks/CU.
// ---------------------------------------------------------------------------
#define S1 168  // row stride (bf16) for K=160 input planes (odd mult of 8)
#define S2 136  // row stride for K=128 planes
__global__ __launch_bounds__(256) void sa2_mfma_kernel(
    const float* __restrict__ xyz1, const float* __restrict__ feat1,
    const float* __restrict__ newXyz, const int* __restrict__ idx,
    const short* __restrict__ w0h, const short* __restrict__ w0l,
    const float* __restrict__ b0,
    const short* __restrict__ w1h, const short* __restrict__ w1l,
    const float* __restrict__ b1,
    const short* __restrict__ w2h, const short* __restrict__ w2l,
    const float* __restrict__ b2,
    float* __restrict__ feat2) {
    const int g = blockIdx.x;
    const int b = g >> 7;
    const int t = threadIdx.x;
    const int lane = t & 63, wv = t >> 6;
    const int lr = lane & 15, lq = lane >> 4;
    const int mh = wv & 1, nh = wv >> 1;
    __shared__ short Ah[64 * S1], Al[64 * S1];   // g input (K=160), later h2
    __shared__ short Hh[64 * S2], Hl[64 * S2];   // h1 (K=128)
    __shared__ float pmax[2][256];
    __shared__ int ids[64];
    if (t < 64) ids[t] = idx[(size_t)g * 64 + t];
    __syncthreads();
    {   // stage gathered input -> bf16 hi/lo planes [m][k], k in [0,160)
        const int m = t >> 2, q = t & 3, k0 = q * 40;
        const int id = ids[m];
        const float* frow = feat1 + ((size_t)b * 512 + id) * 128;
        const float* prow = xyz1 + ((size_t)b * 512 + id) * 3;
        const float* crow = newXyz + (size_t)g * 3;
#pragma unroll
        for (int c8 = 0; c8 < 5; c8++) {
            short8 hv, lv;
#pragma unroll
            for (int j = 0; j < 8; j++) {
                int k = k0 + c8 * 8 + j;
                float v = 0.f;
                if (k < 3) v = prow[k] - crow[k];
                else if (k < 131) v = frow[k - 3];
                short h, l;
                f2bfpair(v, h, l);
                hv[j] = h; lv[j] = l;
            }
            *(short8*)&Ah[m * S1 + k0 + c8 * 8] = hv;
            *(short8*)&Al[m * S1 + k0 + c8 * 8] = lv;
        }
    }
    __syncthreads();
    {   // layer1: K=160 (KS=5), N=128 -> NT=4 per wave
        f32x4 acc[8];
        init_bias<4>(acc, b0, nh * 64, lr);
        mfma_layer<4, 5>(Ah, Al, S1, w0h, w0l, 160, acc, nh * 64, mh, lr, lq);
        store_split<4>(acc, Hh, Hl, S2, nh * 64, mh, lr, lq);
    }
    __syncthreads();
    {   // layer2: K=128 (KS=4), N=128 -> NT=4; output h2 reuses A planes
        f32x4 acc[8];
        init_bias<4>(acc, b1, nh * 64, lr);
        mfma_layer<4, 4>(Hh, Hl, S2, w1h, w1l, 128, acc, nh * 64, mh, lr, lq);
        store_split<4>(acc, Ah, Al, S2, nh * 64, mh, lr, lq);
    }
    __syncthreads();
    {   // layer3: K=128 (KS=4), N=256 -> NT=8 per wave + max over 64 rows
        f32x4 acc[16];
        init_bias<8>(acc, b2, nh * 128, lr);
        mfma_layer<8, 4>(Ah, Al, S2, w2h, w2l, 128, acc, nh * 128, mh, lr, lq);
#pragma unroll
        for (int nt = 0; nt < 8; nt++) {
            float v = 0.f;   // relu floor
#pragma unroll
            for (int mt = 0; mt < 2; mt++)
#pragma unroll
                for (int r = 0; r < 4; r++)
                    v = fmaxf(v, acc[mt * 8 + nt][r]);
            v = fmaxf(v, __shfl_xor(v, 16));
            v = fmaxf(v, __shfl_xor(v, 32));
            if (lane < 16) pmax[mh][nh * 128 + nt * 16 + lane] = v;
        }
    }
    __syncthreads();
    feat2[(size_t)g * 256 + t] = fmaxf(pmax[0][t], pmax[1][t]);
}

// ---------------------------------------------------------------------------
// concat [xyz2(3) | feat2(256)] -> A3 (4096 x 259)
// ---------------------------------------------------------------------------
__global__ void concat3_kernel(const float* __restrict__ xyz2,
                               const float* __restrict__ feat2,
                               float* __restrict__ a3, int total) {
    int i = blockIdx.x * 256 + threadIdx.x;
    if (i >= total) return;
    int m = i / 259, c = i % 259;
    a3[i] = (c < 3) ? xyz2[m * 3 + c] : feat2[m * 256 + (c - 3)];
}

// ---------------------------------------------------------------------------
// GEMM (fp32 vector, unchanged this round)
// ---------------------------------------------------------------------------
template<int RELU>
__global__ __launch_bounds__(256) void gemm_bias_kernel(
    const float* __restrict__ A, const float* __restrict__ W,
    const float* __restrict__ bias, float* __restrict__ out,
    int M, int K, int O) {
    const int bo = blockIdx.x, bm = blockIdx.y;
    const int t = threadIdx.x;
    __shared__ float As[8][132];
    __shared__ float Ws[8][132];
    const int tx = t & 15;
    const int ty = t >> 4;
    const int lr = t >> 1;
    const int lh = (t & 1) * 4;
    const int m0 = bm * 128, o0 = bo * 128;
    float acc[8][8] = {};
    for (int kt = 0; kt < K; kt += 8) {
#pragma unroll
        for (int j = 0; j < 4; j++) {
            int k = kt + lh + j;
            As[lh + j][lr] = (k < K) ? A[(size_t)(m0 + lr) * K + k] : 0.f;
            Ws[lh + j][lr] = (k < K) ? W[(size_t)(o0 + lr) * K + k] : 0.f;
        }
        __syncthreads();
#pragma unroll
        for (int kk = 0; kk < 8; kk++) {
            float a[8], w[8];
#pragma unroll
            for (int i = 0; i < 8; i++) a[i] = As[kk][ty * 8 + i];
#pragma unroll
            for (int i = 0; i < 8; i++) w[i] = Ws[kk][tx * 8 + i];
#pragma unroll
            for (int i = 0; i < 8; i++)
#pragma unroll
                for (int j2 = 0; j2 < 8; j2++)
                    acc[i][j2] += a[i] * w[j2];
        }
        __syncthreads();
    }
#pragma unroll
    for (int i = 0; i < 8; i++) {
        int m = m0 + ty * 8 + i;
#pragma unroll
        for (int j2 = 0; j2 < 8; j2++) {
            int o = o0 + tx * 8 + j2;
            float v = acc[i][j2] + bias[o];
            if (RELU) v = fmaxf(v, 0.f);
            out[(size_t)m * O + o] = v;
        }
    }
}

// ---------------------------------------------------------------------------
// max over 128 points: (32,128,1024) -> (32,1024)
// ---------------------------------------------------------------------------
__global__ void maxpool_kernel(const float* __restrict__ in,
                               float* __restrict__ out) {
    int b = blockIdx.x, t = threadIdx.x;
#pragma unroll
    for (int j = 0; j < 4; j++) {
        int o = t + j * 256;
        float m = -INFINITY;
        for (int k = 0; k < 128; k++)
            m = fmaxf(m, in[((size_t)b * 128 + k) * 1024 + o]);
        out[b * 1024 + o] = m;
    }
}

// ---------------------------------------------------------------------------
// FC head v2: coalesced wave-per-output dot products + softmax.
// ---------------------------------------------------------------------------
__global__ __launch_bounds__(256) void fc_head_kernel(
    const float* __restrict__ gfeat,
    const float* __restrict__ w1, const float* __restrict__ b1,
    const float* __restrict__ w2, const float* __restrict__ b2,
    const float* __restrict__ w3, const float* __restrict__ b3,
    float* __restrict__ out) {
    int b = blockIdx.x, t = threadIdx.x;
    int lane = t & 63, wv = t >> 6;
    __shared__ float f[1024];
    __shared__ float h1[512];
    __shared__ float h2[256];
    __shared__ float lg[40];
    for (int j = t; j < 1024; j += 256) f[j] = gfeat[b * 1024 + j];
    __syncthreads();
    for (int i = 0; i < 128; i++) {          // fc1: 512 outs, 128/wave
        int o = wv * 128 + i;
        const float* wr = w1 + (size_t)o * 1024;
        float a = 0.f;
#pragma unroll
        for (int c = lane; c < 1024; c += 64) a = fmaf(wr[c], f[c], a);
#pragma unroll
        for (int off = 32; off > 0; off >>= 1) a += __shfl_xor(a, off);
        if (lane == 0) h1[o] = fmaxf(a + b1[o], 0.f);
    }
    __syncthreads();
    for (int i = 0; i < 64; i++) {           // fc2: 256 outs, 64/wave
        int o = wv * 64 + i;
        const float* wr = w2 + (size_t)o * 512;
        float a = 0.f;
#pragma unroll
        for (int c = lane; c < 512; c += 64) a = fmaf(wr[c], h1[c], a);
#pragma unroll
        for (int off = 32; off > 0; off >>= 1) a += __shfl_xor(a, off);
        if (lane == 0) h2[o] = fmaxf(a + b2[o], 0.f);
    }
    __syncthreads();
    for (int i = 0; i < 10; i++) {           // fc3: 40 outs, 10/wave
        int o = wv * 10 + i;
        const float* wr = w3 + (size_t)o * 256;
        float a = 0.f;
#pragma unroll
        for (int c = lane; c < 256; c += 64) a = fmaf(wr[c], h2[c], a);
#pragma unroll
        for (int off = 32; off > 0; off >>= 1) a += __shfl_xor(a, off);
        if (lane == 0) lg[o] = a + b3[o];
    }
    __syncthreads();
    if (t < 64) {
        float v = (t < 40) ? lg[t] : -INFINITY;
        float m = v;
#pragma unroll
        for (int off = 32; off > 0; off >>= 1) m = fmaxf(m, __shfl_xor(m, off));
        float e = (t < 40) ? expf(v - m) : 0.f;
        float s = e;
#pragma unroll
        for (int off = 32; off > 0; off >>= 1) s += __shfl_xor(s, off);
        if (t < 40) out[b * 40 + t] = e / s;
    }
}

// ---------------------------------------------------------------------------
extern "C" void kernel_launch(void* const* d_in, const int* in_sizes, int n_in,
                              void* d_out, int out_size, void* d_ws, size_t ws_size,
                              hipStream_t stream) {
    (void)in_sizes; (void)n_in; (void)out_size; (void)ws_size;
    const float* x      = (const float*)d_in[0];
    const float* sa1w0  = (const float*)d_in[1];
    const float* sa1b0  = (const float*)d_in[2];
    const float* sa1w1  = (const float*)d_in[3];
    const float* sa1b1  = (const float*)d_in[4];
    const float* sa1w2  = (const float*)d_in[5];
    const float* sa1b2  = (const float*)d_in[6];
    const float* sa2w0  = (const float*)d_in[7];
    const float* sa2b0  = (const float*)d_in[8];
    const float* sa2w1  = (const float*)d_in[9];
    const float* sa2b1  = (const float*)d_in[10];
    const float* sa2w2  = (const float*)d_in[11];
    const float* sa2b2  = (const float*)d_in[12];
    const float* sa3w0  = (const float*)d_in[13];
    const float* sa3b0  = (const float*)d_in[14];
    const float* sa3w1  = (const float*)d_in[15];
    const float* sa3b1  = (const float*)d_in[16];
    const float* sa3w2  = (const float*)d_in[17];
    const float* sa3b2  = (const float*)d_in[18];
    const float* fc1w   = (const float*)d_in[19];
    const float* fc1b   = (const float*)d_in[20];
    const float* fc2w   = (const float*)d_in[21];
    const float* fc2b   = (const float*)d_in[22];
    const float* fc3w   = (const float*)d_in[23];
    const float* fc3b   = (const float*)d_in[24];
    float* outp = (float*)d_out;

    char* ws = (char*)d_ws;
    size_t off = 0;
    auto alloc = [&](size_t bytes) {
        void* p = ws + off;
        off += (bytes + 255) & ~(size_t)255;
        return p;
    };
    int*   fidx1   = (int*)  alloc((size_t)B_ * 512 * 4);
    float* nxyz1   = (float*)alloc((size_t)B_ * 512 * 3 * 4);
    int*   idx1    = (int*)  alloc((size_t)B_ * 512 * 32 * 4);
    float* feat1   = (float*)alloc((size_t)B_ * 512 * 128 * 4);
    int*   fidx2   = (int*)  alloc((size_t)B_ * 128 * 4);
    float* nxyz2   = (float*)alloc((size_t)B_ * 128 * 3 * 4);
    int*   idx2    = (int*)  alloc((size_t)B_ * 128 * 64 * 4);
    float* feat2   = (float*)alloc((size_t)B_ * 128 * 256 * 4);
    float* a3      = (float*)alloc((size_t)4096 * 259 * 4);
    float* h3a     = (float*)alloc((size_t)4096 * 256 * 4);
    float* h3b     = (float*)alloc((size_t)4096 * 512 * 4);
    float* h3c     = (float*)alloc((size_t)4096 * 1024 * 4);
    float* gfeat   = (float*)alloc((size_t)B_ * 1024 * 4);
    // split-bf16 weight planes
    short* w1h_s1 = (short*)alloc((size_t)64 * 64 * 2);
    short* w1l_s1 = (short*)alloc((size_t)64 * 64 * 2);
    short* w2h_s1 = (short*)alloc((size_t)128 * 64 * 2);
    short* w2l_s1 = (short*)alloc((size_t)128 * 64 * 2);
    short* w0h_s2 = (short*)alloc((size_t)128 * 160 * 2);
    short* w0l_s2 = (short*)alloc((size_t)128 * 160 * 2);
    short* w1h_s2 = (short*)alloc((size_t)128 * 128 * 2);
    short* w1l_s2 = (short*)alloc((size_t)128 * 128 * 2);
    short* w2h_s2 = (short*)alloc((size_t)256 * 128 * 2);
    short* w2l_s2 = (short*)alloc((size_t)256 * 128 * 2);

    // weight prep (independent of data pipeline)
    wprep_kernel<<<(64 * 64 + 255) / 256, 256, 0, stream>>>(
        sa1w1, w1h_s1, w1l_s1, 64, 64, 64);
    wprep_kernel<<<(128 * 64 + 255) / 256, 256, 0, stream>>>(
        sa1w2, w2h_s1, w2l_s1, 128, 64, 64);
    wprep_kernel<<<(128 * 160 + 255) / 256, 256, 0, stream>>>(
        sa2w0, w0h_s2, w0l_s2, 128, 131, 160);
    wprep_kernel<<<(128 * 128 + 255) / 256, 256, 0, stream>>>(
        sa2w1, w1h_s2, w1l_s2, 128, 128, 128);
    wprep_kernel<<<(256 * 128 + 255) / 256, 256, 0, stream>>>(
        sa2w2, w2h_s2, w2l_s2, 256, 128, 128);

    // SA1
    fps_kernel<4096, 512, 512><<<B_, 512, 0, stream>>>(x, fidx1, nxyz1);
    ballquery_kernel<4096, 32, 256, 2><<<B_ * 2, 256, 0, stream>>>(
        x, nxyz1, idx1, 512, 0.04f);
    sa1_mfma_kernel<<<B_ * 512 / 2, 256, 0, stream>>>(
        x, nxyz1, idx1, sa1w0, sa1b0,
        w1h_s1, w1l_s1, sa1b1, w2h_s1, w2l_s1, sa1b2, feat1);
    // SA2
    fps_kernel<512, 128, 64><<<B_, 64, 0, stream>>>(nxyz1, fidx2, nxyz2);
    ballquery_kernel<512, 64, 128, 1><<<B_, 128, 0, stream>>>(
        nxyz1, nxyz2, idx2, 128, 0.16f);
    sa2_mfma_kernel<<<B_ * 128, 256, 0, stream>>>(
        nxyz1, feat1, nxyz2, idx2,
        w0h_s2, w0l_s2, sa2b0, w1h_s2, w1l_s2, sa2b1, w2h_s2, w2l_s2, sa2b2,
        feat2);
    // SA3 (group-all): concat + 3 GEMMs + maxpool
    concat3_kernel<<<(4096 * 259 + 255) / 256, 256, 0, stream>>>(
        nxyz2, feat2, a3, 4096 * 259);
    gemm_bias_kernel<1><<<dim3(2, 32), 256, 0, stream>>>(
        a3, sa3w0, sa3b0, h3a, 4096, 259, 256);
    gemm_bias_kernel<1><<<dim3(4, 32), 256, 0, stream>>>(
        h3a, sa3w1, sa3b1, h3b, 4096, 256, 512);
    gemm_bias_kernel<1><<<dim3(8, 32), 256, 0, stream>>>(
        h3b, sa3w2, sa3b2, h3c, 4096, 512, 1024);
    maxpool_kernel<<<B_, 256, 0, stream>>>(h3c, gfeat);
    // FC head + softmax
    fc_head_kernel<<<B_, 256, 0, stream>>>(
        gfeat, fc1w, fc1b, fc2w, fc2b, fc3w, fc3b, outp);
}

// Round 4
// 2010.528 us; speedup vs baseline: 2.0411x; 1.4516x over previous
//
#include <hip/hip_runtime.h>
#include <math.h>

#define B_ 32
#define N_ 4096

typedef __attribute__((ext_vector_type(8))) short short8;
typedef __attribute__((ext_vector_type(4))) float f32x4;

// fp32 -> bf16 round-to-nearest-even, and split x = hi + lo (both bf16).
__device__ __forceinline__ unsigned short f2bf(float f) {
    unsigned u = __float_as_uint(f);
    unsigned r = 0x7FFFu + ((u >> 16) & 1u);
    return (unsigned short)((u + r) >> 16);
}
__device__ __forceinline__ float bf2f(unsigned short h) {
    return __uint_as_float(((unsigned)h) << 16);
}
__device__ __forceinline__ void f2bfpair(float v, short& h, short& l) {
    unsigned short hh = f2bf(v);
    h = (short)hh;
    l = (short)f2bf(v - bf2f(hh));
}

// ---------------------------------------------------------------------------
// Wave argmax (max value, min index on tie), 4 DPP row_ror stages (VALU
// latency) + 2 ds_swizzle stages. All lanes end with the wave result.
// ---------------------------------------------------------------------------
#define DPP_ARGMAX(ctrl)                                                      \
    {                                                                         \
        float ov = __int_as_float(__builtin_amdgcn_mov_dpp(                   \
            __float_as_int(bv), ctrl, 0xf, 0xf, true));                       \
        int oi = __builtin_amdgcn_mov_dpp(bi, ctrl, 0xf, 0xf, true);          \
        if (ov > bv || (ov == bv && oi < bi)) { bv = ov; bi = oi; }           \
    }

__device__ __forceinline__ void wave_argmax(float& bv, int& bi) {
    DPP_ARGMAX(0x128)   // row_ror:8
    DPP_ARGMAX(0x124)   // row_ror:4
    DPP_ARGMAX(0x122)   // row_ror:2
    DPP_ARGMAX(0x121)   // row_ror:1
#pragma unroll
    for (int off = 16; off <= 32; off <<= 1) {
        float ov = __shfl_xor(bv, off);
        int   oi = __shfl_xor(bi, off);
        if (ov > bv || (ov == bv && oi < bi)) { bv = ov; bi = oi; }
    }
}

// ---------------------------------------------------------------------------
// FPS: one block per batch, exact fp32 math (index-critical).
// One barrier per iteration: wave leaders post to parity-double-buffered
// LDS slots; every thread scans the NW candidates locally.
// ---------------------------------------------------------------------------
template<int N, int NPOINT, int NT>
__global__ void fps_kernel(const float* __restrict__ xyz,
                           int* __restrict__ outIdx,
                           float* __restrict__ outXyz) {
#pragma clang fp contract(off)
    const int b = blockIdx.x;
    const int t = threadIdx.x;
    constexpr int PPT = N / NT;
    constexpr int NW = (NT + 63) / 64;
    __shared__ float xs[N], ys[N], zs[N];
    __shared__ float redV[2][NW];
    __shared__ int   redI[2][NW];
    __shared__ int   fidxS[NPOINT];
    const float* base = xyz + (size_t)b * N * 3;
    for (int j = t; j < N; j += NT) {
        xs[j] = base[j * 3 + 0];
        ys[j] = base[j * 3 + 1];
        zs[j] = base[j * 3 + 2];
    }
    __syncthreads();
    float px[PPT], py[PPT], pz[PPT], mind[PPT];
#pragma unroll
    for (int i = 0; i < PPT; i++) {
        int p = t + i * NT;
        px[i] = xs[p]; py[i] = ys[p]; pz[i] = zs[p];
        mind[i] = 1e10f;
    }
    if (t == 0) fidxS[0] = 0;
    int last = 0;
    for (int it = 1; it < NPOINT; it++) {
        float lx = xs[last], ly = ys[last], lz = zs[last];
        float bv = -1.0f; int bi = 0;
#pragma unroll
        for (int i = 0; i < PPT; i++) {
            float dx = px[i] - lx, dy = py[i] - ly, dz = pz[i] - lz;
            float t0 = dx * dx, t1 = dy * dy, t2 = dz * dz;
            float d = (t0 + t1) + t2;
            float m = fminf(mind[i], d);
            mind[i] = m;
            int p = t + i * NT;
            if (m > bv) { bv = m; bi = p; }   // ascending p => first-max kept
        }
        wave_argmax(bv, bi);
        if constexpr (NT > 64) {
            const int par = it & 1;
            if ((t & 63) == 0) { redV[par][t >> 6] = bv; redI[par][t >> 6] = bi; }
            __syncthreads();
            float fv = redV[par][0]; int fi = redI[par][0];
#pragma unroll
            for (int w = 1; w < NW; w++) {
                float ov = redV[par][w]; int oi = redI[par][w];
                if (ov > fv || (ov == fv && oi < fi)) { fv = ov; fi = oi; }
            }
            last = fi;
            if (t == 0) fidxS[it] = fi;
        } else {
            last = bi;
            if (t == 0) fidxS[it] = bi;
        }
    }
    __syncthreads();
    for (int s = t; s < NPOINT; s += NT) {
        int id = fidxS[s];
        outIdx[b * NPOINT + s] = id;
        outXyz[(b * NPOINT + s) * 3 + 0] = xs[id];
        outXyz[(b * NPOINT + s) * 3 + 1] = ys[id];
        outXyz[(b * NPOINT + s) * 3 + 2] = zs[id];
    }
}

// ---------------------------------------------------------------------------
// Ball query (exact fp32, index-critical — unchanged)
// ---------------------------------------------------------------------------
template<int N, int NS, int NT, int CHUNKS>
__global__ void ballquery_kernel(const float* __restrict__ xyz,
                                 const float* __restrict__ newXyz,
                                 int* __restrict__ outIdx,
                                 int S, float r2) {
#pragma clang fp contract(off)
    const int b = blockIdx.x / CHUNKS;
    const int chunk = blockIdx.x % CHUNKS;
    const int t = threadIdx.x;
    __shared__ float xs[N], ys[N], zs[N];
    const float* base = xyz + (size_t)b * N * 3;
    for (int j = t; j < N; j += NT) {
        xs[j] = base[j * 3 + 0];
        ys[j] = base[j * 3 + 1];
        zs[j] = base[j * 3 + 2];
    }
    __syncthreads();
    const int s = chunk * NT + t;
    const float* q = newXyz + ((size_t)b * S + s) * 3;
    float qx = q[0], qy = q[1], qz = q[2];
    float qn = (qx * qx + qy * qy) + qz * qz;
    int* dst = outIdx + ((size_t)b * S + s) * NS;
    int cnt = 0, first = 0;
    for (int p = 0; p < N; p++) {
        float x = xs[p], y = ys[p], z = zs[p];
        float pn = (x * x + y * y) + z * z;
        float dot = (qx * x + qy * y) + qz * z;
        float sqd = (qn + pn) - 2.0f * dot;
        if (sqd <= r2) {
            if (cnt == 0) first = p;
            dst[cnt++] = p;
            if (cnt == NS) break;
        }
    }
    for (int i = cnt; i < NS; i++) dst[i] = first;
}

// ---------------------------------------------------------------------------
// Weight prep: split fp32 [R][C] into bf16 hi/lo planes [R][Cp] (zero-padded)
// ---------------------------------------------------------------------------
__global__ void wprep_kernel(const float* __restrict__ src,
                             short* __restrict__ dh, short* __restrict__ dl,
                             int R, int C, int Cp) {
    int i = blockIdx.x * 256 + threadIdx.x;
    if (i >= R * Cp) return;
    int r = i / Cp, c = i % Cp;
    float v = (c < C) ? src[r * C + c] : 0.f;
    short h, l;
    f2bfpair(v, h, l);
    dh[i] = h; dl[i] = l;
}

// ---------------------------------------------------------------------------
// MFMA helpers (verified gfx950 16x16x32 bf16 layouts; see R2 comments).
// Split fp32 = hi+lo bf16: D += Ah*Bh + Ah*Bl + Al*Bh
// ---------------------------------------------------------------------------
template<int NT, int KS>
__device__ __forceinline__ void mfma_layer(
    const short* Aph, const short* Apl, const int sA,
    const short* __restrict__ Wph, const short* __restrict__ Wpl, const int sW,
    f32x4* acc, const int n0, const int mh, const int lr, const int lq) {
#pragma unroll
    for (int ks = 0; ks < KS; ks++) {
        const int ka = ks * 32 + lq * 8;
        short8 a_h[2], a_l[2];
#pragma unroll
        for (int mt = 0; mt < 2; mt++) {
            const int m = (mh * 2 + mt) * 16 + lr;
            a_h[mt] = *(const short8*)(Aph + m * sA + ka);
            a_l[mt] = *(const short8*)(Apl + m * sA + ka);
        }
#pragma unroll
        for (int nt = 0; nt < NT; nt++) {
            const int n = n0 + nt * 16 + lr;
            short8 b_h = *(const short8*)(Wph + (size_t)n * sW + ka);
            short8 b_l = *(const short8*)(Wpl + (size_t)n * sW + ka);
#pragma unroll
            for (int mt = 0; mt < 2; mt++) {
                f32x4 c = acc[mt * NT + nt];
                c = __builtin_amdgcn_mfma_f32_16x16x32_bf16(a_h[mt], b_h, c, 0, 0, 0);
                c = __builtin_amdgcn_mfma_f32_16x16x32_bf16(a_h[mt], b_l, c, 0, 0, 0);
                c = __builtin_amdgcn_mfma_f32_16x16x32_bf16(a_l[mt], b_h, c, 0, 0, 0);
                acc[mt * NT + nt] = c;
            }
        }
    }
}

template<int NT>
__device__ __forceinline__ void init_bias(f32x4* acc, const float* __restrict__ bias,
                                          const int n0, const int lr) {
#pragma unroll
    for (int nt = 0; nt < NT; nt++) {
        float bv = bias[n0 + nt * 16 + lr];
        f32x4 c = {bv, bv, bv, bv};
        acc[0 * NT + nt] = c;
        acc[1 * NT + nt] = c;
    }
}

template<int NT>
__device__ __forceinline__ void store_split(
    const f32x4* acc, short* Hp, short* Lp, const int stride,
    const int n0, const int mh, const int lr, const int lq) {
#pragma unroll
    for (int mt = 0; mt < 2; mt++)
#pragma unroll
        for (int nt = 0; nt < NT; nt++)
#pragma unroll
            for (int r = 0; r < 4; r++) {
                float v = fmaxf(acc[mt * NT + nt][r], 0.f);
                short h, l;
                f2bfpair(v, h, l);
                const int m = (mh * 2 + mt) * 16 + lq * 4 + r;
                const int n = n0 + nt * 16 + lr;
                Hp[m * stride + n] = h;
                Lp[m * stride + n] = l;
            }
}

// ---------------------------------------------------------------------------
// SA1 MFMA (unchanged from R2)
// ---------------------------------------------------------------------------
#define T1 72
__global__ __launch_bounds__(256) void sa1_mfma_kernel(
    const float* __restrict__ x, const float* __restrict__ nxyz1,
    const int* __restrict__ idx,
    const float* __restrict__ w0, const float* __restrict__ b0,
    const short* __restrict__ w1h, const short* __restrict__ w1l,
    const float* __restrict__ b1,
    const short* __restrict__ w2h, const short* __restrict__ w2l,
    const float* __restrict__ b2,
    float* __restrict__ feat1) {
    const int g0 = blockIdx.x * 2;
    const int b = g0 >> 9;
    const int t = threadIdx.x;
    const int lane = t & 63, wv = t >> 6;
    const int lr = lane & 15, lq = lane >> 4;
    const int mh = wv & 1, nh = wv >> 1;
    __shared__ float gx[64][4];
    __shared__ short H1h[64 * T1], H1l[64 * T1];
    __shared__ short H2h[64 * T1], H2l[64 * T1];
    if (t < 64) {
        int g = g0 + (t >> 5);
        int id = idx[(size_t)g * 32 + (t & 31)];
        const float* pp = x + ((size_t)b * N_ + id) * 3;
        const float* cc = nxyz1 + (size_t)g * 3;
        gx[t][0] = pp[0] - cc[0];
        gx[t][1] = pp[1] - cc[1];
        gx[t][2] = pp[2] - cc[2];
    }
    __syncthreads();
    {   // layer1 K=3 via VALU
        const int m = t >> 2, oc = (t & 3) * 16;
        float a0 = gx[m][0], a1 = gx[m][1], a2 = gx[m][2];
        short8 hv0, hv1, lv0, lv1;
#pragma unroll
        for (int i = 0; i < 16; i++) {
            int o = oc + i;
            float v = fmaf(w0[o * 3 + 0], a0,
                      fmaf(w0[o * 3 + 1], a1,
                      fmaf(w0[o * 3 + 2], a2, b0[o])));
            v = fmaxf(v, 0.f);
            short h, l;
            f2bfpair(v, h, l);
            if (i < 8) { hv0[i] = h; lv0[i] = l; }
            else       { hv1[i - 8] = h; lv1[i - 8] = l; }
        }
        *(short8*)&H1h[m * T1 + oc]     = hv0;
        *(short8*)&H1h[m * T1 + oc + 8] = hv1;
        *(short8*)&H1l[m * T1 + oc]     = lv0;
        *(short8*)&H1l[m * T1 + oc + 8] = lv1;
    }
    __syncthreads();
    {   // layer2: K=64, N=64
        f32x4 acc[4];
        init_bias<2>(acc, b1, nh * 32, lr);
        mfma_layer<2, 2>(H1h, H1l, T1, w1h, w1l, 64, acc, nh * 32, mh, lr, lq);
        store_split<2>(acc, H2h, H2l, T1, nh * 32, mh, lr, lq);
    }
    __syncthreads();
    {   // layer3: K=64, N=128 + per-group max
        f32x4 acc[8];
        init_bias<4>(acc, b2, nh * 64, lr);
        mfma_layer<4, 2>(H2h, H2l, T1, w2h, w2l, 64, acc, nh * 64, mh, lr, lq);
#pragma unroll
        for (int nt = 0; nt < 4; nt++) {
            float v = 0.f;
#pragma unroll
            for (int mt = 0; mt < 2; mt++)
#pragma unroll
                for (int r = 0; r < 4; r++)
                    v = fmaxf(v, acc[mt * 4 + nt][r]);
            v = fmaxf(v, __shfl_xor(v, 16));
            v = fmaxf(v, __shfl_xor(v, 32));
            if (lane < 16)
                feat1[(size_t)(g0 + mh) * 128 + nh * 64 + nt * 16 + lane] = v;
        }
    }
}

// ---------------------------------------------------------------------------
// SA2 MFMA (unchanged from R2)
// ---------------------------------------------------------------------------
#define S1 168
#define S2 136
__global__ __launch_bounds__(256) void sa2_mfma_kernel(
    const float* __restrict__ xyz1, const float* __restrict__ feat1,
    const float* __restrict__ newXyz, const int* __restrict__ idx,
    const short* __restrict__ w0h, const short* __restrict__ w0l,
    const float* __restrict__ b0,
    const short* __restrict__ w1h, const short* __restrict__ w1l,
    const float* __restrict__ b1,
    const short* __restrict__ w2h, const short* __restrict__ w2l,
    const float* __restrict__ b2,
    float* __restrict__ feat2) {
    const int g = blockIdx.x;
    const int b = g >> 7;
    const int t = threadIdx.x;
    const int lane = t & 63, wv = t >> 6;
    const int lr = lane & 15, lq = lane >> 4;
    const int mh = wv & 1, nh = wv >> 1;
    __shared__ short Ah[64 * S1], Al[64 * S1];
    __shared__ short Hh[64 * S2], Hl[64 * S2];
    __shared__ float pmax[2][256];
    __shared__ int ids[64];
    if (t < 64) ids[t] = idx[(size_t)g * 64 + t];
    __syncthreads();
    {
        const int m = t >> 2, q = t & 3, k0 = q * 40;
        const int id = ids[m];
        const float* frow = feat1 + ((size_t)b * 512 + id) * 128;
        const float* prow = xyz1 + ((size_t)b * 512 + id) * 3;
        const float* crow = newXyz + (size_t)g * 3;
#pragma unroll
        for (int c8 = 0; c8 < 5; c8++) {
            short8 hv, lv;
#pragma unroll
            for (int j = 0; j < 8; j++) {
                int k = k0 + c8 * 8 + j;
                float v = 0.f;
                if (k < 3) v = prow[k] - crow[k];
                else if (k < 131) v = frow[k - 3];
                short h, l;
                f2bfpair(v, h, l);
                hv[j] = h; lv[j] = l;
            }
            *(short8*)&Ah[m * S1 + k0 + c8 * 8] = hv;
            *(short8*)&Al[m * S1 + k0 + c8 * 8] = lv;
        }
    }
    __syncthreads();
    {   // layer1: K=160, N=128
        f32x4 acc[8];
        init_bias<4>(acc, b0, nh * 64, lr);
        mfma_layer<4, 5>(Ah, Al, S1, w0h, w0l, 160, acc, nh * 64, mh, lr, lq);
        store_split<4>(acc, Hh, Hl, S2, nh * 64, mh, lr, lq);
    }
    __syncthreads();
    {   // layer2: K=128, N=128
        f32x4 acc[8];
        init_bias<4>(acc, b1, nh * 64, lr);
        mfma_layer<4, 4>(Hh, Hl, S2, w1h, w1l, 128, acc, nh * 64, mh, lr, lq);
        store_split<4>(acc, Ah, Al, S2, nh * 64, mh, lr, lq);
    }
    __syncthreads();
    {   // layer3: K=128, N=256 + max over 64 rows
        f32x4 acc[16];
        init_bias<8>(acc, b2, nh * 128, lr);
        mfma_layer<8, 4>(Ah, Al, S2, w2h, w2l, 128, acc, nh * 128, mh, lr, lq);
#pragma unroll
        for (int nt = 0; nt < 8; nt++) {
            float v = 0.f;
#pragma unroll
            for (int mt = 0; mt < 2; mt++)
#pragma unroll
                for (int r = 0; r < 4; r++)
                    v = fmaxf(v, acc[mt * 8 + nt][r]);
            v = fmaxf(v, __shfl_xor(v, 16));
            v = fmaxf(v, __shfl_xor(v, 32));
            if (lane < 16) pmax[mh][nh * 128 + nt * 16 + lane] = v;
        }
    }
    __syncthreads();
    feat2[(size_t)g * 256 + t] = fmaxf(pmax[0][t], pmax[1][t]);
}

// ---------------------------------------------------------------------------
// concat [xyz2(3) | feat2(256) | zeros] -> A3 (4096 x 288, zero-padded K)
// ---------------------------------------------------------------------------
__global__ void concat3_kernel(const float* __restrict__ xyz2,
                               const float* __restrict__ feat2,
                               float* __restrict__ a3, int total) {
    int i = blockIdx.x * 256 + threadIdx.x;
    if (i >= total) return;
    int m = i / 288, c = i % 288;
    float v = 0.f;
    if (c < 3) v = xyz2[m * 3 + c];
    else if (c < 259) v = feat2[m * 256 + (c - 3)];
    a3[i] = v;
}

// ---------------------------------------------------------------------------
// MFMA GEMM: out[m][n] = act(bias[n] + sum_k A[m][k]*W[n][k]) via split-bf16.
// A fp32 [M][Kp] (zero-padded), W pre-split planes [N][Kp].
// grid (N/128, M/64), block 256 (4 waves: mh=wv&1 32-row half, nh 64-col half)
// ---------------------------------------------------------------------------
template<int RELU>
__global__ __launch_bounds__(256) void mfma_gemm_kernel(
    const float* __restrict__ A, const int Kp,
    const short* __restrict__ Wh, const short* __restrict__ Wl,
    const float* __restrict__ bias, float* __restrict__ out, const int N) {
    const int t = threadIdx.x;
    const int lane = t & 63, wv = t >> 6;
    const int lr = lane & 15, lq = lane >> 4;
    const int mh = wv & 1, nh = wv >> 1;
    const int m0 = blockIdx.y * 64;
    const int n0 = blockIdx.x * 128 + nh * 64;
    __shared__ short Ah[64 * 40], Al[64 * 40];
    f32x4 acc[8];
#pragma unroll
    for (int nt = 0; nt < 4; nt++) {
        float bv = bias[n0 + nt * 16 + lr];
        f32x4 c = {bv, bv, bv, bv};
        acc[nt] = c; acc[4 + nt] = c;
    }
    const int srow = t >> 2, sk = (t & 3) * 8;
    for (int kt = 0; kt < Kp; kt += 32) {
        {   // stage A chunk: 64 rows x 32 k, split to bf16 hi/lo
            const float* ap = A + (size_t)(m0 + srow) * Kp + kt + sk;
            short8 hv, lv;
#pragma unroll
            for (int j = 0; j < 8; j++) {
                short h, l;
                f2bfpair(ap[j], h, l);
                hv[j] = h; lv[j] = l;
            }
            *(short8*)&Ah[srow * 40 + sk] = hv;
            *(short8*)&Al[srow * 40 + sk] = lv;
        }
        __syncthreads();
        short8 a_h[2], a_l[2];
#pragma unroll
        for (int mt = 0; mt < 2; mt++) {
            const int m = mh * 32 + mt * 16 + lr;
            a_h[mt] = *(const short8*)&Ah[m * 40 + lq * 8];
            a_l[mt] = *(const short8*)&Al[m * 40 + lq * 8];
        }
#pragma unroll
        for (int nt = 0; nt < 4; nt++) {
            const int n = n0 + nt * 16 + lr;
            short8 b_h = *(const short8*)(Wh + (size_t)n * Kp + kt + lq * 8);
            short8 b_l = *(const short8*)(Wl + (size_t)n * Kp + kt + lq * 8);
#pragma unroll
            for (int mt = 0; mt < 2; mt++) {
                f32x4 c = acc[mt * 4 + nt];
                c = __builtin_amdgcn_mfma_f32_16x16x32_bf16(a_h[mt], b_h, c, 0, 0, 0);
                c = __builtin_amdgcn_mfma_f32_16x16x32_bf16(a_h[mt], b_l, c, 0, 0, 0);
                c = __builtin_amdgcn_mfma_f32_16x16x32_bf16(a_l[mt], b_h, c, 0, 0, 0);
                acc[mt * 4 + nt] = c;
            }
        }
        __syncthreads();
    }
#pragma unroll
    for (int mt = 0; mt < 2; mt++)
#pragma unroll
        for (int nt = 0; nt < 4; nt++)
#pragma unroll
            for (int r = 0; r < 4; r++) {
                const int m = m0 + mh * 32 + mt * 16 + lq * 4 + r;
                const int n = n0 + nt * 16 + lr;
                float v = acc[mt * 4 + nt][r];
                if (RELU) v = fmaxf(v, 0.f);
                out[(size_t)m * N + n] = v;
            }
}

// ---------------------------------------------------------------------------
// max over 128 points: (32,128,1024) -> (32,1024)
// ---------------------------------------------------------------------------
__global__ void maxpool_kernel(const float* __restrict__ in,
                               float* __restrict__ out) {
    int b = blockIdx.x, t = threadIdx.x;
#pragma unroll
    for (int j = 0; j < 4; j++) {
        int o = t + j * 256;
        float m = -INFINITY;
        for (int k = 0; k < 128; k++)
            m = fmaxf(m, in[((size_t)b * 128 + k) * 1024 + o]);
        out[b * 1024 + o] = m;
    }
}

// ---------------------------------------------------------------------------
// FC layer: grid (O/(4*OPW), B), block 256. Wave computes OPW outputs via
// lane-strided dots + shfl reduce. Massively more waves than one-block-per-b.
// ---------------------------------------------------------------------------
template<int K, int OPW, int ACT>
__global__ __launch_bounds__(256) void fc_kernel(
    const float* __restrict__ in, const float* __restrict__ w,
    const float* __restrict__ bias, float* __restrict__ out, const int O) {
    const int batch = blockIdx.y;
    const int t = threadIdx.x, lane = t & 63, wv = t >> 6;
    __shared__ float f[K];
    for (int j = t; j < K; j += 256) f[j] = in[batch * K + j];
    __syncthreads();
    const int o0 = blockIdx.x * (4 * OPW) + wv * OPW;
#pragma unroll
    for (int i = 0; i < OPW; i++) {
        const int o = o0 + i;
        const float* wr = w + (size_t)o * K;
        float a = 0.f;
#pragma unroll
        for (int c = lane; c < K; c += 64) a = fmaf(wr[c], f[c], a);
#pragma unroll
        for (int off = 32; off > 0; off >>= 1) a += __shfl_xor(a, off);
        if (lane == 0) {
            float v = a + bias[o];
            out[batch * O + o] = ACT ? fmaxf(v, 0.f) : v;
        }
    }
}

// fc3 (256->40) + softmax fused; one block per batch.
__global__ __launch_bounds__(256) void fc3_softmax_kernel(
    const float* __restrict__ in, const float* __restrict__ w3,
    const float* __restrict__ b3, float* __restrict__ out) {
    const int b = blockIdx.x, t = threadIdx.x, lane = t & 63, wv = t >> 6;
    __shared__ float f[256];
    __shared__ float lg[40];
    f[t] = in[b * 256 + t];
    __syncthreads();
#pragma unroll
    for (int i = 0; i < 10; i++) {
        const int o = wv * 10 + i;
        const float* wr = w3 + (size_t)o * 256;
        float a = 0.f;
#pragma unroll
        for (int c = lane; c < 256; c += 64) a = fmaf(wr[c], f[c], a);
#pragma unroll
        for (int off = 32; off > 0; off >>= 1) a += __shfl_xor(a, off);
        if (lane == 0) lg[o] = a + b3[o];
    }
    __syncthreads();
    if (t < 64) {
        float v = (t < 40) ? lg[t] : -INFINITY;
        float m = v;
#pragma unroll
        for (int off = 32; off > 0; off >>= 1) m = fmaxf(m, __shfl_xor(m, off));
        float e = (t < 40) ? expf(v - m) : 0.f;
        float s = e;
#pragma unroll
        for (int off = 32; off > 0; off >>= 1) s += __shfl_xor(s, off);
        if (t < 40) out[b * 40 + t] = e / s;
    }
}

// ---------------------------------------------------------------------------
extern "C" void kernel_launch(void* const* d_in, const int* in_sizes, int n_in,
                              void* d_out, int out_size, void* d_ws, size_t ws_size,
                              hipStream_t stream) {
    (void)in_sizes; (void)n_in; (void)out_size; (void)ws_size;
    const float* x      = (const float*)d_in[0];
    const float* sa1w0  = (const float*)d_in[1];
    const float* sa1b0  = (const float*)d_in[2];
    const float* sa1w1  = (const float*)d_in[3];
    const float* sa1b1  = (const float*)d_in[4];
    const float* sa1w2  = (const float*)d_in[5];
    const float* sa1b2  = (const float*)d_in[6];
    const float* sa2w0  = (const float*)d_in[7];
    const float* sa2b0  = (const float*)d_in[8];
    const float* sa2w1  = (const float*)d_in[9];
    const float* sa2b1  = (const float*)d_in[10];
    const float* sa2w2  = (const float*)d_in[11];
    const float* sa2b2  = (const float*)d_in[12];
    const float* sa3w0  = (const float*)d_in[13];
    const float* sa3b0  = (const float*)d_in[14];
    const float* sa3w1  = (const float*)d_in[15];
    const float* sa3b1  = (const float*)d_in[16];
    const float* sa3w2  = (const float*)d_in[17];
    const float* sa3b2  = (const float*)d_in[18];
    const float* fc1w   = (const float*)d_in[19];
    const float* fc1b   = (const float*)d_in[20];
    const float* fc2w   = (const float*)d_in[21];
    const float* fc2b   = (const float*)d_in[22];
    const float* fc3w   = (const float*)d_in[23];
    const float* fc3b   = (const float*)d_in[24];
    float* outp = (float*)d_out;

    char* ws = (char*)d_ws;
    size_t off = 0;
    auto alloc = [&](size_t bytes) {
        void* p = ws + off;
        off += (bytes + 255) & ~(size_t)255;
        return p;
    };
    int*   fidx1   = (int*)  alloc((size_t)B_ * 512 * 4);
    float* nxyz1   = (float*)alloc((size_t)B_ * 512 * 3 * 4);
    int*   idx1    = (int*)  alloc((size_t)B_ * 512 * 32 * 4);
    float* feat1   = (float*)alloc((size_t)B_ * 512 * 128 * 4);
    int*   fidx2   = (int*)  alloc((size_t)B_ * 128 * 4);
    float* nxyz2   = (float*)alloc((size_t)B_ * 128 * 3 * 4);
    int*   idx2    = (int*)  alloc((size_t)B_ * 128 * 64 * 4);
    float* feat2   = (float*)alloc((size_t)B_ * 128 * 256 * 4);
    float* a3      = (float*)alloc((size_t)4096 * 288 * 4);
    float* h3a     = (float*)alloc((size_t)4096 * 256 * 4);
    float* h3b     = (float*)alloc((size_t)4096 * 512 * 4);
    float* h3c     = (float*)alloc((size_t)4096 * 1024 * 4);
    float* gfeat   = (float*)alloc((size_t)B_ * 1024 * 4);
    float* h1      = (float*)alloc((size_t)B_ * 512 * 4);
    float* h2      = (float*)alloc((size_t)B_ * 256 * 4);
    // split-bf16 weight planes
    short* w1h_s1 = (short*)alloc((size_t)64 * 64 * 2);
    short* w1l_s1 = (short*)alloc((size_t)64 * 64 * 2);
    short* w2h_s1 = (short*)alloc((size_t)128 * 64 * 2);
    short* w2l_s1 = (short*)alloc((size_t)128 * 64 * 2);
    short* w0h_s2 = (short*)alloc((size_t)128 * 160 * 2);
    short* w0l_s2 = (short*)alloc((size_t)128 * 160 * 2);
    short* w1h_s2 = (short*)alloc((size_t)128 * 128 * 2);
    short* w1l_s2 = (short*)alloc((size_t)128 * 128 * 2);
    short* w2h_s2 = (short*)alloc((size_t)256 * 128 * 2);
    short* w2l_s2 = (short*)alloc((size_t)256 * 128 * 2);
    short* w0h_s3 = (short*)alloc((size_t)256 * 288 * 2);
    short* w0l_s3 = (short*)alloc((size_t)256 * 288 * 2);
    short* w1h_s3 = (short*)alloc((size_t)512 * 256 * 2);
    short* w1l_s3 = (short*)alloc((size_t)512 * 256 * 2);
    short* w2h_s3 = (short*)alloc((size_t)1024 * 512 * 2);
    short* w2l_s3 = (short*)alloc((size_t)1024 * 512 * 2);

    // weight prep
    wprep_kernel<<<(64 * 64 + 255) / 256, 256, 0, stream>>>(
        sa1w1, w1h_s1, w1l_s1, 64, 64, 64);
    wprep_kernel<<<(128 * 64 + 255) / 256, 256, 0, stream>>>(
        sa1w2, w2h_s1, w2l_s1, 128, 64, 64);
    wprep_kernel<<<(128 * 160 + 255) / 256, 256, 0, stream>>>(
        sa2w0, w0h_s2, w0l_s2, 128, 131, 160);
    wprep_kernel<<<(128 * 128 + 255) / 256, 256, 0, stream>>>(
        sa2w1, w1h_s2, w1l_s2, 128, 128, 128);
    wprep_kernel<<<(256 * 128 + 255) / 256, 256, 0, stream>>>(
        sa2w2, w2h_s2, w2l_s2, 256, 128, 128);
    wprep_kernel<<<(256 * 288 + 255) / 256, 256, 0, stream>>>(
        sa3w0, w0h_s3, w0l_s3, 256, 259, 288);
    wprep_kernel<<<(512 * 256 + 255) / 256, 256, 0, stream>>>(
        sa3w1, w1h_s3, w1l_s3, 512, 256, 256);
    wprep_kernel<<<(1024 * 512 + 255) / 256, 256, 0, stream>>>(
        sa3w2, w2h_s3, w2l_s3, 1024, 512, 512);

    // SA1
    fps_kernel<4096, 512, 256><<<B_, 256, 0, stream>>>(x, fidx1, nxyz1);
    ballquery_kernel<4096, 32, 256, 2><<<B_ * 2, 256, 0, stream>>>(
        x, nxyz1, idx1, 512, 0.04f);
    sa1_mfma_kernel<<<B_ * 512 / 2, 256, 0, stream>>>(
        x, nxyz1, idx1, sa1w0, sa1b0,
        w1h_s1, w1l_s1, sa1b1, w2h_s1, w2l_s1, sa1b2, feat1);
    // SA2
    fps_kernel<512, 128, 64><<<B_, 64, 0, stream>>>(nxyz1, fidx2, nxyz2);
    ballquery_kernel<512, 64, 128, 1><<<B_, 128, 0, stream>>>(
        nxyz1, nxyz2, idx2, 128, 0.16f);
    sa2_mfma_kernel<<<B_ * 128, 256, 0, stream>>>(
        nxyz1, feat1, nxyz2, idx2,
        w0h_s2, w0l_s2, sa2b0, w1h_s2, w1l_s2, sa2b1, w2h_s2, w2l_s2, sa2b2,
        feat2);
    // SA3 (group-all): concat + 3 MFMA GEMMs + maxpool
    concat3_kernel<<<(4096 * 288 + 255) / 256, 256, 0, stream>>>(
        nxyz2, feat2, a3, 4096 * 288);
    mfma_gemm_kernel<1><<<dim3(2, 64), 256, 0, stream>>>(
        a3, 288, w0h_s3, w0l_s3, sa3b0, h3a, 256);
    mfma_gemm_kernel<1><<<dim3(4, 64), 256, 0, stream>>>(
        h3a, 256, w1h_s3, w1l_s3, sa3b1, h3b, 512);
    mfma_gemm_kernel<1><<<dim3(8, 64), 256, 0, stream>>>(
        h3b, 512, w2h_s3, w2l_s3, sa3b2, h3c, 1024);
    maxpool_kernel<<<B_, 256, 0, stream>>>(h3c, gfeat);
    // FC head: fc1 (1024->512), fc2 (512->256), fc3+softmax
    fc_kernel<1024, 16, 1><<<dim3(8, B_), 256, 0, stream>>>(
        gfeat, fc1w, fc1b, h1, 512);
    fc_kernel<512, 16, 1><<<dim3(4, B_), 256, 0, stream>>>(
        h1, fc2w, fc2b, h2, 256);
    fc3_softmax_kernel<<<B_, 256, 0, stream>>>(h2, fc3w, fc3b, outp);
}

// Round 5
// 1427.794 us; speedup vs baseline: 2.8741x; 1.4081x over previous
//
#include <hip/hip_runtime.h>
#include <math.h>

#define B_ 32
#define N_ 4096

typedef __attribute__((ext_vector_type(8))) short short8;
typedef __attribute__((ext_vector_type(4))) float f32x4;

// fp32 -> bf16 round-to-nearest-even, and split x = hi + lo (both bf16).
__device__ __forceinline__ unsigned short f2bf(float f) {
    unsigned u = __float_as_uint(f);
    unsigned r = 0x7FFFu + ((u >> 16) & 1u);
    return (unsigned short)((u + r) >> 16);
}
__device__ __forceinline__ float bf2f(unsigned short h) {
    return __uint_as_float(((unsigned)h) << 16);
}
__device__ __forceinline__ void f2bfpair(float v, short& h, short& l) {
    unsigned short hh = f2bf(v);
    h = (short)hh;
    l = (short)f2bf(v - bf2f(hh));
}

// ---------------------------------------------------------------------------
// Wave argmax (max value, min index on tie): 4 DPP row_ror stages + 2 swizzle
// ---------------------------------------------------------------------------
#define DPP_ARGMAX(ctrl)                                                      \
    {                                                                         \
        float ov = __int_as_float(__builtin_amdgcn_mov_dpp(                   \
            __float_as_int(bv), ctrl, 0xf, 0xf, true));                       \
        int oi = __builtin_amdgcn_mov_dpp(bi, ctrl, 0xf, 0xf, true);          \
        if (ov > bv || (ov == bv && oi < bi)) { bv = ov; bi = oi; }           \
    }

__device__ __forceinline__ void wave_argmax(float& bv, int& bi) {
    DPP_ARGMAX(0x128)   // row_ror:8
    DPP_ARGMAX(0x124)   // row_ror:4
    DPP_ARGMAX(0x122)   // row_ror:2
    DPP_ARGMAX(0x121)   // row_ror:1
#pragma unroll
    for (int off = 16; off <= 32; off <<= 1) {
        float ov = __shfl_xor(bv, off);
        int   oi = __shfl_xor(bi, off);
        if (ov > bv || (ov == bv && oi < bi)) { bv = ov; bi = oi; }
    }
}

// ---------------------------------------------------------------------------
// FPS: one block per batch, exact fp32 math (index-critical).
// ---------------------------------------------------------------------------
template<int N, int NPOINT, int NT>
__global__ void fps_kernel(const float* __restrict__ xyz,
                           int* __restrict__ outIdx,
                           float* __restrict__ outXyz) {
#pragma clang fp contract(off)
    const int b = blockIdx.x;
    const int t = threadIdx.x;
    constexpr int PPT = N / NT;
    constexpr int NW = (NT + 63) / 64;
    __shared__ float xs[N], ys[N], zs[N];
    __shared__ float redV[2][NW];
    __shared__ int   redI[2][NW];
    __shared__ int   fidxS[NPOINT];
    const float* base = xyz + (size_t)b * N * 3;
    for (int j = t; j < N; j += NT) {
        xs[j] = base[j * 3 + 0];
        ys[j] = base[j * 3 + 1];
        zs[j] = base[j * 3 + 2];
    }
    __syncthreads();
    float px[PPT], py[PPT], pz[PPT], mind[PPT];
#pragma unroll
    for (int i = 0; i < PPT; i++) {
        int p = t + i * NT;
        px[i] = xs[p]; py[i] = ys[p]; pz[i] = zs[p];
        mind[i] = 1e10f;
    }
    if (t == 0) fidxS[0] = 0;
    int last = 0;
    for (int it = 1; it < NPOINT; it++) {
        float lx = xs[last], ly = ys[last], lz = zs[last];
        float bv = -1.0f; int bi = 0;
#pragma unroll
        for (int i = 0; i < PPT; i++) {
            float dx = px[i] - lx, dy = py[i] - ly, dz = pz[i] - lz;
            float t0 = dx * dx, t1 = dy * dy, t2 = dz * dz;
            float d = (t0 + t1) + t2;
            float m = fminf(mind[i], d);
            mind[i] = m;
            int p = t + i * NT;
            if (m > bv) { bv = m; bi = p; }   // ascending p => first-max kept
        }
        wave_argmax(bv, bi);
        if constexpr (NT > 64) {
            const int par = it & 1;
            if ((t & 63) == 0) { redV[par][t >> 6] = bv; redI[par][t >> 6] = bi; }
            __syncthreads();
            float fv = redV[par][0]; int fi = redI[par][0];
#pragma unroll
            for (int w = 1; w < NW; w++) {
                float ov = redV[par][w]; int oi = redI[par][w];
                if (ov > fv || (ov == fv && oi < fi)) { fv = ov; fi = oi; }
            }
            last = fi;
            if (t == 0) fidxS[it] = fi;
        } else {
            last = bi;
            if (t == 0) fidxS[it] = bi;
        }
    }
    __syncthreads();
    for (int s = t; s < NPOINT; s += NT) {
        int id = fidxS[s];
        outIdx[b * NPOINT + s] = id;
        outXyz[(b * NPOINT + s) * 3 + 0] = xs[id];
        outXyz[(b * NPOINT + s) * 3 + 1] = ys[id];
        outXyz[(b * NPOINT + s) * 3 + 2] = zs[id];
    }
}

// ---------------------------------------------------------------------------
// Ball query v2: wave-per-query. 64 lanes test 64 points per iteration;
// ballot -> mbcnt prefix gives ascending write positions; popcount advances
// wave-uniform cnt; early exit at NS. Exact fp32 math (contract off),
// identical association to reference -> identical index selection.
// ---------------------------------------------------------------------------
template<int N, int NS>
__global__ __launch_bounds__(256) void ballquery_kernel(
    const float* __restrict__ xyz, const float* __restrict__ newXyz,
    int* __restrict__ outIdx, int S, float r2) {
#pragma clang fp contract(off)
    const int qid = blockIdx.x * 4 + (threadIdx.x >> 6);
    const int lane = threadIdx.x & 63;
    const int b = qid / S;
    const float* q = newXyz + (size_t)qid * 3;
    const float qx = q[0], qy = q[1], qz = q[2];
    const float qn = (qx * qx + qy * qy) + qz * qz;
    const float* base = xyz + (size_t)b * N * 3;
    int* dst = outIdx + (size_t)qid * NS;
    int cnt = 0, first = 0;
    for (int p0 = 0; p0 < N; p0 += 64) {
        const int p = p0 + lane;
        const float x = base[p * 3 + 0];
        const float y = base[p * 3 + 1];
        const float z = base[p * 3 + 2];
        const float pn = (x * x + y * y) + z * z;
        const float dot = (qx * x + qy * y) + qz * z;
        const float sqd = (qn + pn) - 2.0f * dot;
        const unsigned long long mask = __ballot(sqd <= r2);
        if (mask) {
            if (cnt == 0) first = p0 + __ffsll((unsigned long long)mask) - 1;
            const int prefix = __builtin_amdgcn_mbcnt_hi(
                (unsigned)(mask >> 32),
                __builtin_amdgcn_mbcnt_lo((unsigned)mask, 0));
            const bool in = (mask >> lane) & 1ull;
            const int pos = cnt + prefix;
            if (in && pos < NS) dst[pos] = p;
            cnt += __popcll(mask);
            if (cnt >= NS) break;
        }
    }
    for (int i = cnt + lane; i < NS; i += 64) dst[i] = first;
}

// ---------------------------------------------------------------------------
// Weight prep: split fp32 [R][C] into bf16 hi/lo planes [R][Cp] (zero-padded)
// ---------------------------------------------------------------------------
__global__ void wprep_kernel(const float* __restrict__ src,
                             short* __restrict__ dh, short* __restrict__ dl,
                             int R, int C, int Cp) {
    int i = blockIdx.x * 256 + threadIdx.x;
    if (i >= R * Cp) return;
    int r = i / Cp, c = i % Cp;
    float v = (c < C) ? src[r * C + c] : 0.f;
    short h, l;
    f2bfpair(v, h, l);
    dh[i] = h; dl[i] = l;
}

// ---------------------------------------------------------------------------
// MFMA helpers (verified gfx950 16x16x32 bf16 layouts).
// Split fp32 = hi+lo bf16: D += Ah*Bh + Ah*Bl + Al*Bh
// ---------------------------------------------------------------------------
template<int NT, int KS>
__device__ __forceinline__ void mfma_layer(
    const short* Aph, const short* Apl, const int sA,
    const short* __restrict__ Wph, const short* __restrict__ Wpl, const int sW,
    f32x4* acc, const int n0, const int mh, const int lr, const int lq) {
#pragma unroll
    for (int ks = 0; ks < KS; ks++) {
        const int ka = ks * 32 + lq * 8;
        short8 a_h[2], a_l[2];
#pragma unroll
        for (int mt = 0; mt < 2; mt++) {
            const int m = (mh * 2 + mt) * 16 + lr;
            a_h[mt] = *(const short8*)(Aph + m * sA + ka);
            a_l[mt] = *(const short8*)(Apl + m * sA + ka);
        }
#pragma unroll
        for (int nt = 0; nt < NT; nt++) {
            const int n = n0 + nt * 16 + lr;
            short8 b_h = *(const short8*)(Wph + (size_t)n * sW + ka);
            short8 b_l = *(const short8*)(Wpl + (size_t)n * sW + ka);
#pragma unroll
            for (int mt = 0; mt < 2; mt++) {
                f32x4 c = acc[mt * NT + nt];
                c = __builtin_amdgcn_mfma_f32_16x16x32_bf16(a_h[mt], b_h, c, 0, 0, 0);
                c = __builtin_amdgcn_mfma_f32_16x16x32_bf16(a_h[mt], b_l, c, 0, 0, 0);
                c = __builtin_amdgcn_mfma_f32_16x16x32_bf16(a_l[mt], b_h, c, 0, 0, 0);
                acc[mt * NT + nt] = c;
            }
        }
    }
}

template<int NT>
__device__ __forceinline__ void init_bias(f32x4* acc, const float* __restrict__ bias,
                                          const int n0, const int lr) {
#pragma unroll
    for (int nt = 0; nt < NT; nt++) {
        float bv = bias[n0 + nt * 16 + lr];
        f32x4 c = {bv, bv, bv, bv};
        acc[0 * NT + nt] = c;
        acc[1 * NT + nt] = c;
    }
}

template<int NT>
__device__ __forceinline__ void store_split(
    const f32x4* acc, short* Hp, short* Lp, const int stride,
    const int n0, const int mh, const int lr, const int lq) {
#pragma unroll
    for (int mt = 0; mt < 2; mt++)
#pragma unroll
        for (int nt = 0; nt < NT; nt++)
#pragma unroll
            for (int r = 0; r < 4; r++) {
                float v = fmaxf(acc[mt * NT + nt][r], 0.f);
                short h, l;
                f2bfpair(v, h, l);
                const int m = (mh * 2 + mt) * 16 + lq * 4 + r;
                const int n = n0 + nt * 16 + lr;
                Hp[m * stride + n] = h;
                Lp[m * stride + n] = l;
            }
}

// ---------------------------------------------------------------------------
// SA1 MFMA (unchanged)
// ---------------------------------------------------------------------------
#define T1 72
__global__ __launch_bounds__(256) void sa1_mfma_kernel(
    const float* __restrict__ x, const float* __restrict__ nxyz1,
    const int* __restrict__ idx,
    const float* __restrict__ w0, const float* __restrict__ b0,
    const short* __restrict__ w1h, const short* __restrict__ w1l,
    const float* __restrict__ b1,
    const short* __restrict__ w2h, const short* __restrict__ w2l,
    const float* __restrict__ b2,
    float* __restrict__ feat1) {
    const int g0 = blockIdx.x * 2;
    const int b = g0 >> 9;
    const int t = threadIdx.x;
    const int lane = t & 63, wv = t >> 6;
    const int lr = lane & 15, lq = lane >> 4;
    const int mh = wv & 1, nh = wv >> 1;
    __shared__ float gx[64][4];
    __shared__ short H1h[64 * T1], H1l[64 * T1];
    __shared__ short H2h[64 * T1], H2l[64 * T1];
    if (t < 64) {
        int g = g0 + (t >> 5);
        int id = idx[(size_t)g * 32 + (t & 31)];
        const float* pp = x + ((size_t)b * N_ + id) * 3;
        const float* cc = nxyz1 + (size_t)g * 3;
        gx[t][0] = pp[0] - cc[0];
        gx[t][1] = pp[1] - cc[1];
        gx[t][2] = pp[2] - cc[2];
    }
    __syncthreads();
    {   // layer1 K=3 via VALU
        const int m = t >> 2, oc = (t & 3) * 16;
        float a0 = gx[m][0], a1 = gx[m][1], a2 = gx[m][2];
        short8 hv0, hv1, lv0, lv1;
#pragma unroll
        for (int i = 0; i < 16; i++) {
            int o = oc + i;
            float v = fmaf(w0[o * 3 + 0], a0,
                      fmaf(w0[o * 3 + 1], a1,
                      fmaf(w0[o * 3 + 2], a2, b0[o])));
            v = fmaxf(v, 0.f);
            short h, l;
            f2bfpair(v, h, l);
            if (i < 8) { hv0[i] = h; lv0[i] = l; }
            else       { hv1[i - 8] = h; lv1[i - 8] = l; }
        }
        *(short8*)&H1h[m * T1 + oc]     = hv0;
        *(short8*)&H1h[m * T1 + oc + 8] = hv1;
        *(short8*)&H1l[m * T1 + oc]     = lv0;
        *(short8*)&H1l[m * T1 + oc + 8] = lv1;
    }
    __syncthreads();
    {   // layer2: K=64, N=64
        f32x4 acc[4];
        init_bias<2>(acc, b1, nh * 32, lr);
        mfma_layer<2, 2>(H1h, H1l, T1, w1h, w1l, 64, acc, nh * 32, mh, lr, lq);
        store_split<2>(acc, H2h, H2l, T1, nh * 32, mh, lr, lq);
    }
    __syncthreads();
    {   // layer3: K=64, N=128 + per-group max
        f32x4 acc[8];
        init_bias<4>(acc, b2, nh * 64, lr);
        mfma_layer<4, 2>(H2h, H2l, T1, w2h, w2l, 64, acc, nh * 64, mh, lr, lq);
#pragma unroll
        for (int nt = 0; nt < 4; nt++) {
            float v = 0.f;
#pragma unroll
            for (int mt = 0; mt < 2; mt++)
#pragma unroll
                for (int r = 0; r < 4; r++)
                    v = fmaxf(v, acc[mt * 4 + nt][r]);
            v = fmaxf(v, __shfl_xor(v, 16));
            v = fmaxf(v, __shfl_xor(v, 32));
            if (lane < 16)
                feat1[(size_t)(g0 + mh) * 128 + nh * 64 + nt * 16 + lane] = v;
        }
    }
}

// ---------------------------------------------------------------------------
// SA2 MFMA (unchanged)
// ---------------------------------------------------------------------------
#define S1 168
#define S2 136
__global__ __launch_bounds__(256) void sa2_mfma_kernel(
    const float* __restrict__ xyz1, const float* __restrict__ feat1,
    const float* __restrict__ newXyz, const int* __restrict__ idx,
    const short* __restrict__ w0h, const short* __restrict__ w0l,
    const float* __restrict__ b0,
    const short* __restrict__ w1h, const short* __restrict__ w1l,
    const float* __restrict__ b1,
    const short* __restrict__ w2h, const short* __restrict__ w2l,
    const float* __restrict__ b2,
    float* __restrict__ feat2) {
    const int g = blockIdx.x;
    const int b = g >> 7;
    const int t = threadIdx.x;
    const int lane = t & 63, wv = t >> 6;
    const int lr = lane & 15, lq = lane >> 4;
    const int mh = wv & 1, nh = wv >> 1;
    __shared__ short Ah[64 * S1], Al[64 * S1];
    __shared__ short Hh[64 * S2], Hl[64 * S2];
    __shared__ float pmax[2][256];
    __shared__ int ids[64];
    if (t < 64) ids[t] = idx[(size_t)g * 64 + t];
    __syncthreads();
    {
        const int m = t >> 2, q = t & 3, k0 = q * 40;
        const int id = ids[m];
        const float* frow = feat1 + ((size_t)b * 512 + id) * 128;
        const float* prow = xyz1 + ((size_t)b * 512 + id) * 3;
        const float* crow = newXyz + (size_t)g * 3;
#pragma unroll
        for (int c8 = 0; c8 < 5; c8++) {
            short8 hv, lv;
#pragma unroll
            for (int j = 0; j < 8; j++) {
                int k = k0 + c8 * 8 + j;
                float v = 0.f;
                if (k < 3) v = prow[k] - crow[k];
                else if (k < 131) v = frow[k - 3];
                short h, l;
                f2bfpair(v, h, l);
                hv[j] = h; lv[j] = l;
            }
            *(short8*)&Ah[m * S1 + k0 + c8 * 8] = hv;
            *(short8*)&Al[m * S1 + k0 + c8 * 8] = lv;
        }
    }
    __syncthreads();
    {   // layer1: K=160, N=128
        f32x4 acc[8];
        init_bias<4>(acc, b0, nh * 64, lr);
        mfma_layer<4, 5>(Ah, Al, S1, w0h, w0l, 160, acc, nh * 64, mh, lr, lq);
        store_split<4>(acc, Hh, Hl, S2, nh * 64, mh, lr, lq);
    }
    __syncthreads();
    {   // layer2: K=128, N=128
        f32x4 acc[8];
        init_bias<4>(acc, b1, nh * 64, lr);
        mfma_layer<4, 4>(Hh, Hl, S2, w1h, w1l, 128, acc, nh * 64, mh, lr, lq);
        store_split<4>(acc, Ah, Al, S2, nh * 64, mh, lr, lq);
    }
    __syncthreads();
    {   // layer3: K=128, N=256 + max over 64 rows
        f32x4 acc[16];
        init_bias<8>(acc, b2, nh * 128, lr);
        mfma_layer<8, 4>(Ah, Al, S2, w2h, w2l, 128, acc, nh * 128, mh, lr, lq);
#pragma unroll
        for (int nt = 0; nt < 8; nt++) {
            float v = 0.f;
#pragma unroll
            for (int mt = 0; mt < 2; mt++)
#pragma unroll
                for (int r = 0; r < 4; r++)
                    v = fmaxf(v, acc[mt * 8 + nt][r]);
            v = fmaxf(v, __shfl_xor(v, 16));
            v = fmaxf(v, __shfl_xor(v, 32));
            if (lane < 16) pmax[mh][nh * 128 + nt * 16 + lane] = v;
        }
    }
    __syncthreads();
    feat2[(size_t)g * 256 + t] = fmaxf(pmax[0][t], pmax[1][t]);
}

// ---------------------------------------------------------------------------
// concat [xyz2(3) | feat2(256) | zeros] -> A3 (4096 x 288, zero-padded K)
// ---------------------------------------------------------------------------
__global__ void concat3_kernel(const float* __restrict__ xyz2,
                               const float* __restrict__ feat2,
                               float* __restrict__ a3, int total) {
    int i = blockIdx.x * 256 + threadIdx.x;
    if (i >= total) return;
    int m = i / 288, c = i % 288;
    float v = 0.f;
    if (c < 3) v = xyz2[m * 3 + c];
    else if (c < 259) v = feat2[m * 256 + (c - 3)];
    a3[i] = v;
}

// ---------------------------------------------------------------------------
// MFMA GEMM (unchanged)
// ---------------------------------------------------------------------------
template<int RELU>
__global__ __launch_bounds__(256) void mfma_gemm_kernel(
    const float* __restrict__ A, const int Kp,
    const short* __restrict__ Wh, const short* __restrict__ Wl,
    const float* __restrict__ bias, float* __restrict__ out, const int N) {
    const int t = threadIdx.x;
    const int lane = t & 63, wv = t >> 6;
    const int lr = lane & 15, lq = lane >> 4;
    const int mh = wv & 1, nh = wv >> 1;
    const int m0 = blockIdx.y * 64;
    const int n0 = blockIdx.x * 128 + nh * 64;
    __shared__ short Ah[64 * 40], Al[64 * 40];
    f32x4 acc[8];
#pragma unroll
    for (int nt = 0; nt < 4; nt++) {
        float bv = bias[n0 + nt * 16 + lr];
        f32x4 c = {bv, bv, bv, bv};
        acc[nt] = c; acc[4 + nt] = c;
    }
    const int srow = t >> 2, sk = (t & 3) * 8;
    for (int kt = 0; kt < Kp; kt += 32) {
        {
            const float* ap = A + (size_t)(m0 + srow) * Kp + kt + sk;
            short8 hv, lv;
#pragma unroll
            for (int j = 0; j < 8; j++) {
                short h, l;
                f2bfpair(ap[j], h, l);
                hv[j] = h; lv[j] = l;
            }
            *(short8*)&Ah[srow * 40 + sk] = hv;
            *(short8*)&Al[srow * 40 + sk] = lv;
        }
        __syncthreads();
        short8 a_h[2], a_l[2];
#pragma unroll
        for (int mt = 0; mt < 2; mt++) {
            const int m = mh * 32 + mt * 16 + lr;
            a_h[mt] = *(const short8*)&Ah[m * 40 + lq * 8];
            a_l[mt] = *(const short8*)&Al[m * 40 + lq * 8];
        }
#pragma unroll
        for (int nt = 0; nt < 4; nt++) {
            const int n = n0 + nt * 16 + lr;
            short8 b_h = *(const short8*)(Wh + (size_t)n * Kp + kt + lq * 8);
            short8 b_l = *(const short8*)(Wl + (size_t)n * Kp + kt + lq * 8);
#pragma unroll
            for (int mt = 0; mt < 2; mt++) {
                f32x4 c = acc[mt * 4 + nt];
                c = __builtin_amdgcn_mfma_f32_16x16x32_bf16(a_h[mt], b_h, c, 0, 0, 0);
                c = __builtin_amdgcn_mfma_f32_16x16x32_bf16(a_h[mt], b_l, c, 0, 0, 0);
                c = __builtin_amdgcn_mfma_f32_16x16x32_bf16(a_l[mt], b_h, c, 0, 0, 0);
                acc[mt * 4 + nt] = c;
            }
        }
        __syncthreads();
    }
#pragma unroll
    for (int mt = 0; mt < 2; mt++)
#pragma unroll
        for (int nt = 0; nt < 4; nt++)
#pragma unroll
            for (int r = 0; r < 4; r++) {
                const int m = m0 + mh * 32 + mt * 16 + lq * 4 + r;
                const int n = n0 + nt * 16 + lr;
                float v = acc[mt * 4 + nt][r];
                if (RELU) v = fmaxf(v, 0.f);
                out[(size_t)m * N + n] = v;
            }
}

// ---------------------------------------------------------------------------
// max over 128 points: (32,128,1024) -> (32,1024)
// ---------------------------------------------------------------------------
__global__ void maxpool_kernel(const float* __restrict__ in,
                               float* __restrict__ out) {
    int b = blockIdx.x, t = threadIdx.x;
#pragma unroll
    for (int j = 0; j < 4; j++) {
        int o = t + j * 256;
        float m = -INFINITY;
        for (int k = 0; k < 128; k++)
            m = fmaxf(m, in[((size_t)b * 128 + k) * 1024 + o]);
        out[b * 1024 + o] = m;
    }
}

// ---------------------------------------------------------------------------
// FC layer: grid (O/(4*OPW), B), block 256.
// ---------------------------------------------------------------------------
template<int K, int OPW, int ACT>
__global__ __launch_bounds__(256) void fc_kernel(
    const float* __restrict__ in, const float* __restrict__ w,
    const float* __restrict__ bias, float* __restrict__ out, const int O) {
    const int batch = blockIdx.y;
    const int t = threadIdx.x, lane = t & 63, wv = t >> 6;
    __shared__ float f[K];
    for (int j = t; j < K; j += 256) f[j] = in[batch * K + j];
    __syncthreads();
    const int o0 = blockIdx.x * (4 * OPW) + wv * OPW;
#pragma unroll
    for (int i = 0; i < OPW; i++) {
        const int o = o0 + i;
        const float* wr = w + (size_t)o * K;
        float a = 0.f;
#pragma unroll
        for (int c = lane; c < K; c += 64) a = fmaf(wr[c], f[c], a);
#pragma unroll
        for (int off = 32; off > 0; off >>= 1) a += __shfl_xor(a, off);
        if (lane == 0) {
            float v = a + bias[o];
            out[batch * O + o] = ACT ? fmaxf(v, 0.f) : v;
        }
    }
}

// fc3 (256->40) + softmax fused; one block per batch.
__global__ __launch_bounds__(256) void fc3_softmax_kernel(
    const float* __restrict__ in, const float* __restrict__ w3,
    const float* __restrict__ b3, float* __restrict__ out) {
    const int b = blockIdx.x, t = threadIdx.x, lane = t & 63, wv = t >> 6;
    __shared__ float f[256];
    __shared__ float lg[40];
    f[t] = in[b * 256 + t];
    __syncthreads();
#pragma unroll
    for (int i = 0; i < 10; i++) {
        const int o = wv * 10 + i;
        const float* wr = w3 + (size_t)o * 256;
        float a = 0.f;
#pragma unroll
        for (int c = lane; c < 256; c += 64) a = fmaf(wr[c], f[c], a);
#pragma unroll
        for (int off = 32; off > 0; off >>= 1) a += __shfl_xor(a, off);
        if (lane == 0) lg[o] = a + b3[o];
    }
    __syncthreads();
    if (t < 64) {
        float v = (t < 40) ? lg[t] : -INFINITY;
        float m = v;
#pragma unroll
        for (int off = 32; off > 0; off >>= 1) m = fmaxf(m, __shfl_xor(m, off));
        float e = (t < 40) ? expf(v - m) : 0.f;
        float s = e;
#pragma unroll
        for (int off = 32; off > 0; off >>= 1) s += __shfl_xor(s, off);
        if (t < 40) out[b * 40 + t] = e / s;
    }
}

// ---------------------------------------------------------------------------
extern "C" void kernel_launch(void* const* d_in, const int* in_sizes, int n_in,
                              void* d_out, int out_size, void* d_ws, size_t ws_size,
                              hipStream_t stream) {
    (void)in_sizes; (void)n_in; (void)out_size; (void)ws_size;
    const float* x      = (const float*)d_in[0];
    const float* sa1w0  = (const float*)d_in[1];
    const float* sa1b0  = (const float*)d_in[2];
    const float* sa1w1  = (const float*)d_in[3];
    const float* sa1b1  = (const float*)d_in[4];
    const float* sa1w2  = (const float*)d_in[5];
    const float* sa1b2  = (const float*)d_in[6];
    const float* sa2w0  = (const float*)d_in[7];
    const float* sa2b0  = (const float*)d_in[8];
    const float* sa2w1  = (const float*)d_in[9];
    const float* sa2b1  = (const float*)d_in[10];
    const float* sa2w2  = (const float*)d_in[11];
    const float* sa2b2  = (const float*)d_in[12];
    const float* sa3w0  = (const float*)d_in[13];
    const float* sa3b0  = (const float*)d_in[14];
    const float* sa3w1  = (const float*)d_in[15];
    const float* sa3b1  = (const float*)d_in[16];
    const float* sa3w2  = (const float*)d_in[17];
    const float* sa3b2  = (const float*)d_in[18];
    const float* fc1w   = (const float*)d_in[19];
    const float* fc1b   = (const float*)d_in[20];
    const float* fc2w   = (const float*)d_in[21];
    const float* fc2b   = (const float*)d_in[22];
    const float* fc3w   = (const float*)d_in[23];
    const float* fc3b   = (const float*)d_in[24];
    float* outp = (float*)d_out;

    char* ws = (char*)d_ws;
    size_t off = 0;
    auto alloc = [&](size_t bytes) {
        void* p = ws + off;
        off += (bytes + 255) & ~(size_t)255;
        return p;
    };
    int*   fidx1   = (int*)  alloc((size_t)B_ * 512 * 4);
    float* nxyz1   = (float*)alloc((size_t)B_ * 512 * 3 * 4);
    int*   idx1    = (int*)  alloc((size_t)B_ * 512 * 32 * 4);
    float* feat1   = (float*)alloc((size_t)B_ * 512 * 128 * 4);
    int*   fidx2   = (int*)  alloc((size_t)B_ * 128 * 4);
    float* nxyz2   = (float*)alloc((size_t)B_ * 128 * 3 * 4);
    int*   idx2    = (int*)  alloc((size_t)B_ * 128 * 64 * 4);
    float* feat2   = (float*)alloc((size_t)B_ * 128 * 256 * 4);
    float* a3      = (float*)alloc((size_t)4096 * 288 * 4);
    float* h3a     = (float*)alloc((size_t)4096 * 256 * 4);
    float* h3b     = (float*)alloc((size_t)4096 * 512 * 4);
    float* h3c     = (float*)alloc((size_t)4096 * 1024 * 4);
    float* gfeat   = (float*)alloc((size_t)B_ * 1024 * 4);
    float* h1      = (float*)alloc((size_t)B_ * 512 * 4);
    float* h2      = (float*)alloc((size_t)B_ * 256 * 4);
    // split-bf16 weight planes
    short* w1h_s1 = (short*)alloc((size_t)64 * 64 * 2);
    short* w1l_s1 = (short*)alloc((size_t)64 * 64 * 2);
    short* w2h_s1 = (short*)alloc((size_t)128 * 64 * 2);
    short* w2l_s1 = (short*)alloc((size_t)128 * 64 * 2);
    short* w0h_s2 = (short*)alloc((size_t)128 * 160 * 2);
    short* w0l_s2 = (short*)alloc((size_t)128 * 160 * 2);
    short* w1h_s2 = (short*)alloc((size_t)128 * 128 * 2);
    short* w1l_s2 = (short*)alloc((size_t)128 * 128 * 2);
    short* w2h_s2 = (short*)alloc((size_t)256 * 128 * 2);
    short* w2l_s2 = (short*)alloc((size_t)256 * 128 * 2);
    short* w0h_s3 = (short*)alloc((size_t)256 * 288 * 2);
    short* w0l_s3 = (short*)alloc((size_t)256 * 288 * 2);
    short* w1h_s3 = (short*)alloc((size_t)512 * 256 * 2);
    short* w1l_s3 = (short*)alloc((size_t)512 * 256 * 2);
    short* w2h_s3 = (short*)alloc((size_t)1024 * 512 * 2);
    short* w2l_s3 = (short*)alloc((size_t)1024 * 512 * 2);

    // weight prep
    wprep_kernel<<<(64 * 64 + 255) / 256, 256, 0, stream>>>(
        sa1w1, w1h_s1, w1l_s1, 64, 64, 64);
    wprep_kernel<<<(128 * 64 + 255) / 256, 256, 0, stream>>>(
        sa1w2, w2h_s1, w2l_s1, 128, 64, 64);
    wprep_kernel<<<(128 * 160 + 255) / 256, 256, 0, stream>>>(
        sa2w0, w0h_s2, w0l_s2, 128, 131, 160);
    wprep_kernel<<<(128 * 128 + 255) / 256, 256, 0, stream>>>(
        sa2w1, w1h_s2, w1l_s2, 128, 128, 128);
    wprep_kernel<<<(256 * 128 + 255) / 256, 256, 0, stream>>>(
        sa2w2, w2h_s2, w2l_s2, 256, 128, 128);
    wprep_kernel<<<(256 * 288 + 255) / 256, 256, 0, stream>>>(
        sa3w0, w0h_s3, w0l_s3, 256, 259, 288);
    wprep_kernel<<<(512 * 256 + 255) / 256, 256, 0, stream>>>(
        sa3w1, w1h_s3, w1l_s3, 512, 256, 256);
    wprep_kernel<<<(1024 * 512 + 255) / 256, 256, 0, stream>>>(
        sa3w2, w2h_s3, w2l_s3, 1024, 512, 512);

    // SA1
    fps_kernel<4096, 512, 256><<<B_, 256, 0, stream>>>(x, fidx1, nxyz1);
    ballquery_kernel<4096, 32><<<B_ * 512 / 4, 256, 0, stream>>>(
        x, nxyz1, idx1, 512, 0.04f);
    sa1_mfma_kernel<<<B_ * 512 / 2, 256, 0, stream>>>(
        x, nxyz1, idx1, sa1w0, sa1b0,
        w1h_s1, w1l_s1, sa1b1, w2h_s1, w2l_s1, sa1b2, feat1);
    // SA2
    fps_kernel<512, 128, 64><<<B_, 64, 0, stream>>>(nxyz1, fidx2, nxyz2);
    ballquery_kernel<512, 64><<<B_ * 128 / 4, 256, 0, stream>>>(
        nxyz1, nxyz2, idx2, 128, 0.16f);
    sa2_mfma_kernel<<<B_ * 128, 256, 0, stream>>>(
        nxyz1, feat1, nxyz2, idx2,
        w0h_s2, w0l_s2, sa2b0, w1h_s2, w1l_s2, sa2b1, w2h_s2, w2l_s2, sa2b2,
        feat2);
    // SA3 (group-all): concat + 3 MFMA GEMMs + maxpool
    concat3_kernel<<<(4096 * 288 + 255) / 256, 256, 0, stream>>>(
        nxyz2, feat2, a3, 4096 * 288);
    mfma_gemm_kernel<1><<<dim3(2, 64), 256, 0, stream>>>(
        a3, 288, w0h_s3, w0l_s3, sa3b0, h3a, 256);
    mfma_gemm_kernel<1><<<dim3(4, 64), 256, 0, stream>>>(
        h3a, 256, w1h_s3, w1l_s3, sa3b1, h3b, 512);
    mfma_gemm_kernel<1><<<dim3(8, 64), 256, 0, stream>>>(
        h3b, 512, w2h_s3, w2l_s3, sa3b2, h3c, 1024);
    maxpool_kernel<<<B_, 256, 0, stream>>>(h3c, gfeat);
    // FC head: fc1 (1024->512), fc2 (512->256), fc3+softmax
    fc_kernel<1024, 16, 1><<<dim3(8, B_), 256, 0, stream>>>(
        gfeat, fc1w, fc1b, h1, 512);
    fc_kernel<512, 16, 1><<<dim3(4, B_), 256, 0, stream>>>(
        h1, fc2w, fc2b, h2, 256);
    fc3_softmax_kernel<<<B_, 256, 0, stream>>>(h2, fc3w, fc3b, outp);
}

// Round 6
// 1406.268 us; speedup vs baseline: 2.9181x; 1.0153x over previous
//
#include <hip/hip_runtime.h>
#include <math.h>

#define B_ 32
#define N_ 4096

typedef __attribute__((ext_vector_type(8))) short short8;
typedef __attribute__((ext_vector_type(4))) float f32x4;

// fp32 -> bf16 round-to-nearest-even, and split x = hi + lo (both bf16).
__device__ __forceinline__ unsigned short f2bf(float f) {
    unsigned u = __float_as_uint(f);
    unsigned r = 0x7FFFu + ((u >> 16) & 1u);
    return (unsigned short)((u + r) >> 16);
}
__device__ __forceinline__ float bf2f(unsigned short h) {
    return __uint_as_float(((unsigned)h) << 16);
}
__device__ __forceinline__ void f2bfpair(float v, short& h, short& l) {
    unsigned short hh = f2bf(v);
    h = (short)hh;
    l = (short)f2bf(v - bf2f(hh));
}

// ---------------------------------------------------------------------------
// Wave argmax (max value, min index on tie): 4 DPP row_ror stages + 2 swizzle
// ---------------------------------------------------------------------------
#define DPP_ARGMAX(ctrl)                                                      \
    {                                                                         \
        float ov = __int_as_float(__builtin_amdgcn_mov_dpp(                   \
            __float_as_int(bv), ctrl, 0xf, 0xf, true));                       \
        int oi = __builtin_amdgcn_mov_dpp(bi, ctrl, 0xf, 0xf, true);          \
        if (ov > bv || (ov == bv && oi < bi)) { bv = ov; bi = oi; }           \
    }

__device__ __forceinline__ void wave_argmax(float& bv, int& bi) {
    DPP_ARGMAX(0x128)   // row_ror:8
    DPP_ARGMAX(0x124)   // row_ror:4
    DPP_ARGMAX(0x122)   // row_ror:2
    DPP_ARGMAX(0x121)   // row_ror:1
#pragma unroll
    for (int off = 16; off <= 32; off <<= 1) {
        float ov = __shfl_xor(bv, off);
        int   oi = __shfl_xor(bi, off);
        if (ov > bv || (ov == bv && oi < bi)) { bv = ov; bi = oi; }
    }
}

// ---------------------------------------------------------------------------
// FPS: one block per batch, exact fp32 math (index-critical).
// Grid is only B_ blocks -> occupancy can never exceed 1 block/CU, so
// __launch_bounds__(NT,1) frees the register allocator; asm pins stop the
// compiler rematerializing px/py/pz from LDS every iteration (R5: VGPR=40
// proved it was re-reading 48 floats/iter from LDS).
// ---------------------------------------------------------------------------
template<int N, int NPOINT, int NT>
__global__ __launch_bounds__(NT, 1) void fps_kernel(
    const float* __restrict__ xyz,
    int* __restrict__ outIdx,
    float* __restrict__ outXyz) {
#pragma clang fp contract(off)
    const int b = blockIdx.x;
    const int t = threadIdx.x;
    constexpr int PPT = N / NT;
    constexpr int NW = (NT + 63) / 64;
    __shared__ float xs[N], ys[N], zs[N];
    __shared__ float redV[2][NW];
    __shared__ int   redI[2][NW];
    __shared__ int   fidxS[NPOINT];
    const float* base = xyz + (size_t)b * N * 3;
    for (int j = t; j < N; j += NT) {
        xs[j] = base[j * 3 + 0];
        ys[j] = base[j * 3 + 1];
        zs[j] = base[j * 3 + 2];
    }
    __syncthreads();
    float px[PPT], py[PPT], pz[PPT], mind[PPT];
#pragma unroll
    for (int i = 0; i < PPT; i++) {
        int p = t + i * NT;
        px[i] = xs[p]; py[i] = ys[p]; pz[i] = zs[p];
        mind[i] = 1e10f;
    }
    // pin coordinate arrays in VGPRs (opaque to remat)
#pragma unroll
    for (int i = 0; i < PPT; i++)
        asm volatile("" : "+v"(px[i]), "+v"(py[i]), "+v"(pz[i]));
    if (t == 0) fidxS[0] = 0;
    int last = 0;
    for (int it = 1; it < NPOINT; it++) {
        float lx = xs[last], ly = ys[last], lz = zs[last];
        float bv = -1.0f; int bi = 0;
#pragma unroll
        for (int i = 0; i < PPT; i++) {
            float dx = px[i] - lx, dy = py[i] - ly, dz = pz[i] - lz;
            float t0 = dx * dx, t1 = dy * dy, t2 = dz * dz;
            float d = (t0 + t1) + t2;
            float m = fminf(mind[i], d);
            mind[i] = m;
            int p = t + i * NT;
            if (m > bv) { bv = m; bi = p; }   // ascending p => first-max kept
        }
        wave_argmax(bv, bi);
        if constexpr (NT > 64) {
            const int par = it & 1;
            if ((t & 63) == 0) { redV[par][t >> 6] = bv; redI[par][t >> 6] = bi; }
            __syncthreads();
            float fv = redV[par][0]; int fi = redI[par][0];
#pragma unroll
            for (int w = 1; w < NW; w++) {
                float ov = redV[par][w]; int oi = redI[par][w];
                if (ov > fv || (ov == fv && oi < fi)) { fv = ov; fi = oi; }
            }
            last = fi;
            if (t == 0) fidxS[it] = fi;
        } else {
            last = bi;
            if (t == 0) fidxS[it] = bi;
        }
    }
    __syncthreads();
    for (int s = t; s < NPOINT; s += NT) {
        int id = fidxS[s];
        outIdx[b * NPOINT + s] = id;
        outXyz[(b * NPOINT + s) * 3 + 0] = xs[id];
        outXyz[(b * NPOINT + s) * 3 + 1] = ys[id];
        outXyz[(b * NPOINT + s) * 3 + 2] = zs[id];
    }
}

// ---------------------------------------------------------------------------
// Ball query: wave-per-query (ballot/mbcnt), exact fp32 math.
// ---------------------------------------------------------------------------
template<int N, int NS>
__global__ __launch_bounds__(256) void ballquery_kernel(
    const float* __restrict__ xyz, const float* __restrict__ newXyz,
    int* __restrict__ outIdx, int S, float r2) {
#pragma clang fp contract(off)
    const int qid = blockIdx.x * 4 + (threadIdx.x >> 6);
    const int lane = threadIdx.x & 63;
    const int b = qid / S;
    const float* q = newXyz + (size_t)qid * 3;
    const float qx = q[0], qy = q[1], qz = q[2];
    const float qn = (qx * qx + qy * qy) + qz * qz;
    const float* base = xyz + (size_t)b * N * 3;
    int* dst = outIdx + (size_t)qid * NS;
    int cnt = 0, first = 0;
    for (int p0 = 0; p0 < N; p0 += 64) {
        const int p = p0 + lane;
        const float x = base[p * 3 + 0];
        const float y = base[p * 3 + 1];
        const float z = base[p * 3 + 2];
        const float pn = (x * x + y * y) + z * z;
        const float dot = (qx * x + qy * y) + qz * z;
        const float sqd = (qn + pn) - 2.0f * dot;
        const unsigned long long mask = __ballot(sqd <= r2);
        if (mask) {
            if (cnt == 0) first = p0 + __ffsll((unsigned long long)mask) - 1;
            const int prefix = __builtin_amdgcn_mbcnt_hi(
                (unsigned)(mask >> 32),
                __builtin_amdgcn_mbcnt_lo((unsigned)mask, 0));
            const bool in = (mask >> lane) & 1ull;
            const int pos = cnt + prefix;
            if (in && pos < NS) dst[pos] = p;
            cnt += __popcll(mask);
            if (cnt >= NS) break;
        }
    }
    for (int i = cnt + lane; i < NS; i += 64) dst[i] = first;
}

// ---------------------------------------------------------------------------
// Weight prep: split fp32 [R][C] into bf16 hi/lo planes [R][Cp] (zero-padded)
// ---------------------------------------------------------------------------
__global__ void wprep_kernel(const float* __restrict__ src,
                             short* __restrict__ dh, short* __restrict__ dl,
                             int R, int C, int Cp) {
    int i = blockIdx.x * 256 + threadIdx.x;
    if (i >= R * Cp) return;
    int r = i / Cp, c = i % Cp;
    float v = (c < C) ? src[r * C + c] : 0.f;
    short h, l;
    f2bfpair(v, h, l);
    dh[i] = h; dl[i] = l;
}

// ---------------------------------------------------------------------------
// MFMA helpers (verified gfx950 16x16x32 bf16 layouts).
// Split fp32 = hi+lo bf16: D += Ah*Bh + Ah*Bl + Al*Bh
// ---------------------------------------------------------------------------
template<int NT, int KS>
__device__ __forceinline__ void mfma_layer(
    const short* Aph, const short* Apl, const int sA,
    const short* __restrict__ Wph, const short* __restrict__ Wpl, const int sW,
    f32x4* acc, const int n0, const int mh, const int lr, const int lq) {
#pragma unroll
    for (int ks = 0; ks < KS; ks++) {
        const int ka = ks * 32 + lq * 8;
        short8 a_h[2], a_l[2];
#pragma unroll
        for (int mt = 0; mt < 2; mt++) {
            const int m = (mh * 2 + mt) * 16 + lr;
            a_h[mt] = *(const short8*)(Aph + m * sA + ka);
            a_l[mt] = *(const short8*)(Apl + m * sA + ka);
        }
#pragma unroll
        for (int nt = 0; nt < NT; nt++) {
            const int n = n0 + nt * 16 + lr;
            short8 b_h = *(const short8*)(Wph + (size_t)n * sW + ka);
            short8 b_l = *(const short8*)(Wpl + (size_t)n * sW + ka);
#pragma unroll
            for (int mt = 0; mt < 2; mt++) {
                f32x4 c = acc[mt * NT + nt];
                c = __builtin_amdgcn_mfma_f32_16x16x32_bf16(a_h[mt], b_h, c, 0, 0, 0);
                c = __builtin_amdgcn_mfma_f32_16x16x32_bf16(a_h[mt], b_l, c, 0, 0, 0);
                c = __builtin_amdgcn_mfma_f32_16x16x32_bf16(a_l[mt], b_h, c, 0, 0, 0);
                acc[mt * NT + nt] = c;
            }
        }
    }
}

template<int NT>
__device__ __forceinline__ void init_bias(f32x4* acc, const float* __restrict__ bias,
                                          const int n0, const int lr) {
#pragma unroll
    for (int nt = 0; nt < NT; nt++) {
        float bv = bias[n0 + nt * 16 + lr];
        f32x4 c = {bv, bv, bv, bv};
        acc[0 * NT + nt] = c;
        acc[1 * NT + nt] = c;
    }
}

template<int NT>
__device__ __forceinline__ void store_split(
    const f32x4* acc, short* Hp, short* Lp, const int stride,
    const int n0, const int mh, const int lr, const int lq) {
#pragma unroll
    for (int mt = 0; mt < 2; mt++)
#pragma unroll
        for (int nt = 0; nt < NT; nt++)
#pragma unroll
            for (int r = 0; r < 4; r++) {
                float v = fmaxf(acc[mt * NT + nt][r], 0.f);
                short h, l;
                f2bfpair(v, h, l);
                const int m = (mh * 2 + mt) * 16 + lq * 4 + r;
                const int n = n0 + nt * 16 + lr;
                Hp[m * stride + n] = h;
                Lp[m * stride + n] = l;
            }
}

// ---------------------------------------------------------------------------
// SA1 MFMA (unchanged)
// ---------------------------------------------------------------------------
#define T1 72
__global__ __launch_bounds__(256) void sa1_mfma_kernel(
    const float* __restrict__ x, const float* __restrict__ nxyz1,
    const int* __restrict__ idx,
    const float* __restrict__ w0, const float* __restrict__ b0,
    const short* __restrict__ w1h, const short* __restrict__ w1l,
    const float* __restrict__ b1,
    const short* __restrict__ w2h, const short* __restrict__ w2l,
    const float* __restrict__ b2,
    float* __restrict__ feat1) {
    const int g0 = blockIdx.x * 2;
    const int b = g0 >> 9;
    const int t = threadIdx.x;
    const int lane = t & 63, wv = t >> 6;
    const int lr = lane & 15, lq = lane >> 4;
    const int mh = wv & 1, nh = wv >> 1;
    __shared__ float gx[64][4];
    __shared__ short H1h[64 * T1], H1l[64 * T1];
    __shared__ short H2h[64 * T1], H2l[64 * T1];
    if (t < 64) {
        int g = g0 + (t >> 5);
        int id = idx[(size_t)g * 32 + (t & 31)];
        const float* pp = x + ((size_t)b * N_ + id) * 3;
        const float* cc = nxyz1 + (size_t)g * 3;
        gx[t][0] = pp[0] - cc[0];
        gx[t][1] = pp[1] - cc[1];
        gx[t][2] = pp[2] - cc[2];
    }
    __syncthreads();
    {   // layer1 K=3 via VALU
        const int m = t >> 2, oc = (t & 3) * 16;
        float a0 = gx[m][0], a1 = gx[m][1], a2 = gx[m][2];
        short8 hv0, hv1, lv0, lv1;
#pragma unroll
        for (int i = 0; i < 16; i++) {
            int o = oc + i;
            float v = fmaf(w0[o * 3 + 0], a0,
                      fmaf(w0[o * 3 + 1], a1,
                      fmaf(w0[o * 3 + 2], a2, b0[o])));
            v = fmaxf(v, 0.f);
            short h, l;
            f2bfpair(v, h, l);
            if (i < 8) { hv0[i] = h; lv0[i] = l; }
            else       { hv1[i - 8] = h; lv1[i - 8] = l; }
        }
        *(short8*)&H1h[m * T1 + oc]     = hv0;
        *(short8*)&H1h[m * T1 + oc + 8] = hv1;
        *(short8*)&H1l[m * T1 + oc]     = lv0;
        *(short8*)&H1l[m * T1 + oc + 8] = lv1;
    }
    __syncthreads();
    {   // layer2: K=64, N=64
        f32x4 acc[4];
        init_bias<2>(acc, b1, nh * 32, lr);
        mfma_layer<2, 2>(H1h, H1l, T1, w1h, w1l, 64, acc, nh * 32, mh, lr, lq);
        store_split<2>(acc, H2h, H2l, T1, nh * 32, mh, lr, lq);
    }
    __syncthreads();
    {   // layer3: K=64, N=128 + per-group max
        f32x4 acc[8];
        init_bias<4>(acc, b2, nh * 64, lr);
        mfma_layer<4, 2>(H2h, H2l, T1, w2h, w2l, 64, acc, nh * 64, mh, lr, lq);
#pragma unroll
        for (int nt = 0; nt < 4; nt++) {
            float v = 0.f;
#pragma unroll
            for (int mt = 0; mt < 2; mt++)
#pragma unroll
                for (int r = 0; r < 4; r++)
                    v = fmaxf(v, acc[mt * 4 + nt][r]);
            v = fmaxf(v, __shfl_xor(v, 16));
            v = fmaxf(v, __shfl_xor(v, 32));
            if (lane < 16)
                feat1[(size_t)(g0 + mh) * 128 + nh * 64 + nt * 16 + lane] = v;
        }
    }
}

// ---------------------------------------------------------------------------
// SA2 MFMA (unchanged)
// ---------------------------------------------------------------------------
#define S1 168
#define S2 136
__global__ __launch_bounds__(256) void sa2_mfma_kernel(
    const float* __restrict__ xyz1, const float* __restrict__ feat1,
    const float* __restrict__ newXyz, const int* __restrict__ idx,
    const short* __restrict__ w0h, const short* __restrict__ w0l,
    const float* __restrict__ b0,
    const short* __restrict__ w1h, const short* __restrict__ w1l,
    const float* __restrict__ b1,
    const short* __restrict__ w2h, const short* __restrict__ w2l,
    const float* __restrict__ b2,
    float* __restrict__ feat2) {
    const int g = blockIdx.x;
    const int b = g >> 7;
    const int t = threadIdx.x;
    const int lane = t & 63, wv = t >> 6;
    const int lr = lane & 15, lq = lane >> 4;
    const int mh = wv & 1, nh = wv >> 1;
    __shared__ short Ah[64 * S1], Al[64 * S1];
    __shared__ short Hh[64 * S2], Hl[64 * S2];
    __shared__ float pmax[2][256];
    __shared__ int ids[64];
    if (t < 64) ids[t] = idx[(size_t)g * 64 + t];
    __syncthreads();
    {
        const int m = t >> 2, q = t & 3, k0 = q * 40;
        const int id = ids[m];
        const float* frow = feat1 + ((size_t)b * 512 + id) * 128;
        const float* prow = xyz1 + ((size_t)b * 512 + id) * 3;
        const float* crow = newXyz + (size_t)g * 3;
#pragma unroll
        for (int c8 = 0; c8 < 5; c8++) {
            short8 hv, lv;
#pragma unroll
            for (int j = 0; j < 8; j++) {
                int k = k0 + c8 * 8 + j;
                float v = 0.f;
                if (k < 3) v = prow[k] - crow[k];
                else if (k < 131) v = frow[k - 3];
                short h, l;
                f2bfpair(v, h, l);
                hv[j] = h; lv[j] = l;
            }
            *(short8*)&Ah[m * S1 + k0 + c8 * 8] = hv;
            *(short8*)&Al[m * S1 + k0 + c8 * 8] = lv;
        }
    }
    __syncthreads();
    {   // layer1: K=160, N=128
        f32x4 acc[8];
        init_bias<4>(acc, b0, nh * 64, lr);
        mfma_layer<4, 5>(Ah, Al, S1, w0h, w0l, 160, acc, nh * 64, mh, lr, lq);
        store_split<4>(acc, Hh, Hl, S2, nh * 64, mh, lr, lq);
    }
    __syncthreads();
    {   // layer2: K=128, N=128
        f32x4 acc[8];
        init_bias<4>(acc, b1, nh * 64, lr);
        mfma_layer<4, 4>(Hh, Hl, S2, w1h, w1l, 128, acc, nh * 64, mh, lr, lq);
        store_split<4>(acc, Ah, Al, S2, nh * 64, mh, lr, lq);
    }
    __syncthreads();
    {   // layer3: K=128, N=256 + max over 64 rows
        f32x4 acc[16];
        init_bias<8>(acc, b2, nh * 128, lr);
        mfma_layer<8, 4>(Ah, Al, S2, w2h, w2l, 128, acc, nh * 128, mh, lr, lq);
#pragma unroll
        for (int nt = 0; nt < 8; nt++) {
            float v = 0.f;
#pragma unroll
            for (int mt = 0; mt < 2; mt++)
#pragma unroll
                for (int r = 0; r < 4; r++)
                    v = fmaxf(v, acc[mt * 8 + nt][r]);
            v = fmaxf(v, __shfl_xor(v, 16));
            v = fmaxf(v, __shfl_xor(v, 32));
            if (lane < 16) pmax[mh][nh * 128 + nt * 16 + lane] = v;
        }
    }
    __syncthreads();
    feat2[(size_t)g * 256 + t] = fmaxf(pmax[0][t], pmax[1][t]);
}

// ---------------------------------------------------------------------------
// concat [xyz2(3) | feat2(256) | zeros] -> A3 (4096 x 288, zero-padded K)
// ---------------------------------------------------------------------------
__global__ void concat3_kernel(const float* __restrict__ xyz2,
                               const float* __restrict__ feat2,
                               float* __restrict__ a3, int total) {
    int i = blockIdx.x * 256 + threadIdx.x;
    if (i >= total) return;
    int m = i / 288, c = i % 288;
    float v = 0.f;
    if (c < 3) v = xyz2[m * 3 + c];
    else if (c < 259) v = feat2[m * 256 + (c - 3)];
    a3[i] = v;
}

// ---------------------------------------------------------------------------
// MFMA GEMM (unchanged)
// ---------------------------------------------------------------------------
template<int RELU>
__global__ __launch_bounds__(256) void mfma_gemm_kernel(
    const float* __restrict__ A, const int Kp,
    const short* __restrict__ Wh, const short* __restrict__ Wl,
    const float* __restrict__ bias, float* __restrict__ out, const int N) {
    const int t = threadIdx.x;
    const int lane = t & 63, wv = t >> 6;
    const int lr = lane & 15, lq = lane >> 4;
    const int mh = wv & 1, nh = wv >> 1;
    const int m0 = blockIdx.y * 64;
    const int n0 = blockIdx.x * 128 + nh * 64;
    __shared__ short Ah[64 * 40], Al[64 * 40];
    f32x4 acc[8];
#pragma unroll
    for (int nt = 0; nt < 4; nt++) {
        float bv = bias[n0 + nt * 16 + lr];
        f32x4 c = {bv, bv, bv, bv};
        acc[nt] = c; acc[4 + nt] = c;
    }
    const int srow = t >> 2, sk = (t & 3) * 8;
    for (int kt = 0; kt < Kp; kt += 32) {
        {
            const float* ap = A + (size_t)(m0 + srow) * Kp + kt + sk;
            short8 hv, lv;
#pragma unroll
            for (int j = 0; j < 8; j++) {
                short h, l;
                f2bfpair(ap[j], h, l);
                hv[j] = h; lv[j] = l;
            }
            *(short8*)&Ah[srow * 40 + sk] = hv;
            *(short8*)&Al[srow * 40 + sk] = lv;
        }
        __syncthreads();
        short8 a_h[2], a_l[2];
#pragma unroll
        for (int mt = 0; mt < 2; mt++) {
            const int m = mh * 32 + mt * 16 + lr;
            a_h[mt] = *(const short8*)&Ah[m * 40 + lq * 8];
            a_l[mt] = *(const short8*)&Al[m * 40 + lq * 8];
        }
#pragma unroll
        for (int nt = 0; nt < 4; nt++) {
            const int n = n0 + nt * 16 + lr;
            short8 b_h = *(const short8*)(Wh + (size_t)n * Kp + kt + lq * 8);
            short8 b_l = *(const short8*)(Wl + (size_t)n * Kp + kt + lq * 8);
#pragma unroll
            for (int mt = 0; mt < 2; mt++) {
                f32x4 c = acc[mt * 4 + nt];
                c = __builtin_amdgcn_mfma_f32_16x16x32_bf16(a_h[mt], b_h, c, 0, 0, 0);
                c = __builtin_amdgcn_mfma_f32_16x16x32_bf16(a_h[mt], b_l, c, 0, 0, 0);
                c = __builtin_amdgcn_mfma_f32_16x16x32_bf16(a_l[mt], b_h, c, 0, 0, 0);
                acc[mt * 4 + nt] = c;
            }
        }
        __syncthreads();
    }
#pragma unroll
    for (int mt = 0; mt < 2; mt++)
#pragma unroll
        for (int nt = 0; nt < 4; nt++)
#pragma unroll
            for (int r = 0; r < 4; r++) {
                const int m = m0 + mh * 32 + mt * 16 + lq * 4 + r;
                const int n = n0 + nt * 16 + lr;
                float v = acc[mt * 4 + nt][r];
                if (RELU) v = fmaxf(v, 0.f);
                out[(size_t)m * N + n] = v;
            }
}

// ---------------------------------------------------------------------------
// max over 128 points: (32,128,1024) -> (32,1024)
// ---------------------------------------------------------------------------
__global__ void maxpool_kernel(const float* __restrict__ in,
                               float* __restrict__ out) {
    int b = blockIdx.x, t = threadIdx.x;
#pragma unroll
    for (int j = 0; j < 4; j++) {
        int o = t + j * 256;
        float m = -INFINITY;
        for (int k = 0; k < 128; k++)
            m = fmaxf(m, in[((size_t)b * 128 + k) * 1024 + o]);
        out[b * 1024 + o] = m;
    }
}

// ---------------------------------------------------------------------------
// FC layer: grid (O/(4*OPW), B), block 256.
// ---------------------------------------------------------------------------
template<int K, int OPW, int ACT>
__global__ __launch_bounds__(256) void fc_kernel(
    const float* __restrict__ in, const float* __restrict__ w,
    const float* __restrict__ bias, float* __restrict__ out, const int O) {
    const int batch = blockIdx.y;
    const int t = threadIdx.x, lane = t & 63, wv = t >> 6;
    __shared__ float f[K];
    for (int j = t; j < K; j += 256) f[j] = in[batch * K + j];
    __syncthreads();
    const int o0 = blockIdx.x * (4 * OPW) + wv * OPW;
#pragma unroll
    for (int i = 0; i < OPW; i++) {
        const int o = o0 + i;
        const float* wr = w + (size_t)o * K;
        float a = 0.f;
#pragma unroll
        for (int c = lane; c < K; c += 64) a = fmaf(wr[c], f[c], a);
#pragma unroll
        for (int off = 32; off > 0; off >>= 1) a += __shfl_xor(a, off);
        if (lane == 0) {
            float v = a + bias[o];
            out[batch * O + o] = ACT ? fmaxf(v, 0.f) : v;
        }
    }
}

// fc3 (256->40) + softmax fused; one block per batch.
__global__ __launch_bounds__(256) void fc3_softmax_kernel(
    const float* __restrict__ in, const float* __restrict__ w3,
    const float* __restrict__ b3, float* __restrict__ out) {
    const int b = blockIdx.x, t = threadIdx.x, lane = t & 63, wv = t >> 6;
    __shared__ float f[256];
    __shared__ float lg[40];
    f[t] = in[b * 256 + t];
    __syncthreads();
#pragma unroll
    for (int i = 0; i < 10; i++) {
        const int o = wv * 10 + i;
        const float* wr = w3 + (size_t)o * 256;
        float a = 0.f;
#pragma unroll
        for (int c = lane; c < 256; c += 64) a = fmaf(wr[c], f[c], a);
#pragma unroll
        for (int off = 32; off > 0; off >>= 1) a += __shfl_xor(a, off);
        if (lane == 0) lg[o] = a + b3[o];
    }
    __syncthreads();
    if (t < 64) {
        float v = (t < 40) ? lg[t] : -INFINITY;
        float m = v;
#pragma unroll
        for (int off = 32; off > 0; off >>= 1) m = fmaxf(m, __shfl_xor(m, off));
        float e = (t < 40) ? expf(v - m) : 0.f;
        float s = e;
#pragma unroll
        for (int off = 32; off > 0; off >>= 1) s += __shfl_xor(s, off);
        if (t < 40) out[b * 40 + t] = e / s;
    }
}

// ---------------------------------------------------------------------------
extern "C" void kernel_launch(void* const* d_in, const int* in_sizes, int n_in,
                              void* d_out, int out_size, void* d_ws, size_t ws_size,
                              hipStream_t stream) {
    (void)in_sizes; (void)n_in; (void)out_size; (void)ws_size;
    const float* x      = (const float*)d_in[0];
    const float* sa1w0  = (const float*)d_in[1];
    const float* sa1b0  = (const float*)d_in[2];
    const float* sa1w1  = (const float*)d_in[3];
    const float* sa1b1  = (const float*)d_in[4];
    const float* sa1w2  = (const float*)d_in[5];
    const float* sa1b2  = (const float*)d_in[6];
    const float* sa2w0  = (const float*)d_in[7];
    const float* sa2b0  = (const float*)d_in[8];
    const float* sa2w1  = (const float*)d_in[9];
    const float* sa2b1  = (const float*)d_in[10];
    const float* sa2w2  = (const float*)d_in[11];
    const float* sa2b2  = (const float*)d_in[12];
    const float* sa3w0  = (const float*)d_in[13];
    const float* sa3b0  = (const float*)d_in[14];
    const float* sa3w1  = (const float*)d_in[15];
    const float* sa3b1  = (const float*)d_in[16];
    const float* sa3w2  = (const float*)d_in[17];
    const float* sa3b2  = (const float*)d_in[18];
    const float* fc1w   = (const float*)d_in[19];
    const float* fc1b   = (const float*)d_in[20];
    const float* fc2w   = (const float*)d_in[21];
    const float* fc2b   = (const float*)d_in[22];
    const float* fc3w   = (const float*)d_in[23];
    const float* fc3b   = (const float*)d_in[24];
    float* outp = (float*)d_out;

    char* ws = (char*)d_ws;
    size_t off = 0;
    auto alloc = [&](size_t bytes) {
        void* p = ws + off;
        off += (bytes + 255) & ~(size_t)255;
        return p;
    };
    int*   fidx1   = (int*)  alloc((size_t)B_ * 512 * 4);
    float* nxyz1   = (float*)alloc((size_t)B_ * 512 * 3 * 4);
    int*   idx1    = (int*)  alloc((size_t)B_ * 512 * 32 * 4);
    float* feat1   = (float*)alloc((size_t)B_ * 512 * 128 * 4);
    int*   fidx2   = (int*)  alloc((size_t)B_ * 128 * 4);
    float* nxyz2   = (float*)alloc((size_t)B_ * 128 * 3 * 4);
    int*   idx2    = (int*)  alloc((size_t)B_ * 128 * 64 * 4);
    float* feat2   = (float*)alloc((size_t)B_ * 128 * 256 * 4);
    float* a3      = (float*)alloc((size_t)4096 * 288 * 4);
    float* h3a     = (float*)alloc((size_t)4096 * 256 * 4);
    float* h3b     = (float*)alloc((size_t)4096 * 512 * 4);
    float* h3c     = (float*)alloc((size_t)4096 * 1024 * 4);
    float* gfeat   = (float*)alloc((size_t)B_ * 1024 * 4);
    float* h1      = (float*)alloc((size_t)B_ * 512 * 4);
    float* h2      = (float*)alloc((size_t)B_ * 256 * 4);
    // split-bf16 weight planes
    short* w1h_s1 = (short*)alloc((size_t)64 * 64 * 2);
    short* w1l_s1 = (short*)alloc((size_t)64 * 64 * 2);
    short* w2h_s1 = (short*)alloc((size_t)128 * 64 * 2);
    short* w2l_s1 = (short*)alloc((size_t)128 * 64 * 2);
    short* w0h_s2 = (short*)alloc((size_t)128 * 160 * 2);
    short* w0l_s2 = (short*)alloc((size_t)128 * 160 * 2);
    short* w1h_s2 = (short*)alloc((size_t)128 * 128 * 2);
    short* w1l_s2 = (short*)alloc((size_t)128 * 128 * 2);
    short* w2h_s2 = (short*)alloc((size_t)256 * 128 * 2);
    short* w2l_s2 = (short*)alloc((size_t)256 * 128 * 2);
    short* w0h_s3 = (short*)alloc((size_t)256 * 288 * 2);
    short* w0l_s3 = (short*)alloc((size_t)256 * 288 * 2);
    short* w1h_s3 = (short*)alloc((size_t)512 * 256 * 2);
    short* w1l_s3 = (short*)alloc((size_t)512 * 256 * 2);
    short* w2h_s3 = (short*)alloc((size_t)1024 * 512 * 2);
    short* w2l_s3 = (short*)alloc((size_t)1024 * 512 * 2);

    // weight prep
    wprep_kernel<<<(64 * 64 + 255) / 256, 256, 0, stream>>>(
        sa1w1, w1h_s1, w1l_s1, 64, 64, 64);
    wprep_kernel<<<(128 * 64 + 255) / 256, 256, 0, stream>>>(
        sa1w2, w2h_s1, w2l_s1, 128, 64, 64);
    wprep_kernel<<<(128 * 160 + 255) / 256, 256, 0, stream>>>(
        sa2w0, w0h_s2, w0l_s2, 128, 131, 160);
    wprep_kernel<<<(128 * 128 + 255) / 256, 256, 0, stream>>>(
        sa2w1, w1h_s2, w1l_s2, 128, 128, 128);
    wprep_kernel<<<(256 * 128 + 255) / 256, 256, 0, stream>>>(
        sa2w2, w2h_s2, w2l_s2, 256, 128, 128);
    wprep_kernel<<<(256 * 288 + 255) / 256, 256, 0, stream>>>(
        sa3w0, w0h_s3, w0l_s3, 256, 259, 288);
    wprep_kernel<<<(512 * 256 + 255) / 256, 256, 0, stream>>>(
        sa3w1, w1h_s3, w1l_s3, 512, 256, 256);
    wprep_kernel<<<(1024 * 512 + 255) / 256, 256, 0, stream>>>(
        sa3w2, w2h_s3, w2l_s3, 1024, 512, 512);

    // SA1
    fps_kernel<4096, 512, 256><<<B_, 256, 0, stream>>>(x, fidx1, nxyz1);
    ballquery_kernel<4096, 32><<<B_ * 512 / 4, 256, 0, stream>>>(
        x, nxyz1, idx1, 512, 0.04f);
    sa1_mfma_kernel<<<B_ * 512 / 2, 256, 0, stream>>>(
        x, nxyz1, idx1, sa1w0, sa1b0,
        w1h_s1, w1l_s1, sa1b1, w2h_s1, w2l_s1, sa1b2, feat1);
    // SA2
    fps_kernel<512, 128, 64><<<B_, 64, 0, stream>>>(nxyz1, fidx2, nxyz2);
    ballquery_kernel<512, 64><<<B_ * 128 / 4, 256, 0, stream>>>(
        nxyz1, nxyz2, idx2, 128, 0.16f);
    sa2_mfma_kernel<<<B_ * 128, 256, 0, stream>>>(
        nxyz1, feat1, nxyz2, idx2,
        w0h_s2, w0l_s2, sa2b0, w1h_s2, w1l_s2, sa2b1, w2h_s2, w2l_s2, sa2b2,
        feat2);
    // SA3 (group-all): concat + 3 MFMA GEMMs + maxpool
    concat3_kernel<<<(4096 * 288 + 255) / 256, 256, 0, stream>>>(
        nxyz2, feat2, a3, 4096 * 288);
    mfma_gemm_kernel<1><<<dim3(2, 64), 256, 0, stream>>>(
        a3, 288, w0h_s3, w0l_s3, sa3b0, h3a, 256);
    mfma_gemm_kernel<1><<<dim3(4, 64), 256, 0, stream>>>(
        h3a, 256, w1h_s3, w1l_s3, sa3b1, h3b, 512);
    mfma_gemm_kernel<1><<<dim3(8, 64), 256, 0, stream>>>(
        h3b, 512, w2h_s3, w2l_s3, sa3b2, h3c, 1024);
    maxpool_kernel<<<B_, 256, 0, stream>>>(h3c, gfeat);
    // FC head: fc1 (1024->512), fc2 (512->256), fc3+softmax
    fc_kernel<1024, 16, 1><<<dim3(8, B_), 256, 0, stream>>>(
        gfeat, fc1w, fc1b, h1, 512);
    fc_kernel<512, 16, 1><<<dim3(4, B_), 256, 0, stream>>>(
        h1, fc2w, fc2b, h2, 256);
    fc3_softmax_kernel<<<B_, 256, 0, stream>>>(h2, fc3w, fc3b, outp);
}